// Round 2
// baseline (867.447 us; speedup 1.0000x reference)
//
#include <hip/hip_runtime.h>
#include <hip/hip_bf16.h>

using bf16 = __hip_bfloat16;

#define B_  4
#define H_  56
#define W_  56
#define N_  3136
#define C_  256
#define NH  8
#define HD  32
#define P_  49
#define PH  7
#define ROWS 8

__device__ __forceinline__ float ldS(const float* p, size_t i) { return p[i]; }
__device__ __forceinline__ float ldS(const bf16*  p, size_t i) { return __bfloat162float(p[i]); }
__device__ __forceinline__ void  stS(float* p, size_t i, float v) { p[i] = v; }
__device__ __forceinline__ void  stS(bf16*  p, size_t i, float v) { p[i] = __float2bfloat16(v); }

// butterfly sum over each 32-lane half of a 64-lane wave
__device__ __forceinline__ float half_reduce(float v) {
#pragma unroll
    for (int m = 16; m >= 1; m >>= 1) v += __shfl_xor(v, m);
    return v;
}

// block (256 threads) sum; red must be float[4] shared
__device__ __forceinline__ float block_sum(float val, float* red) {
#pragma unroll
    for (int m = 32; m >= 1; m >>= 1) val += __shfl_xor(val, m);
    __syncthreads();
    if ((threadIdx.x & 63) == 0) red[threadIdx.x >> 6] = val;
    __syncthreads();
    return red[0] + red[1] + red[2] + red[3];
}

// ---------------- kernel A: q/k/v projection + per-head normalize (8 rows/block) ----------------
template <typename S>
__global__ __launch_bounds__(256) void k_qkv(
    const float* __restrict__ x,
    const float* __restrict__ Wq, const float* __restrict__ bq,
    const float* __restrict__ Wkv, const float* __restrict__ bkv,
    S* __restrict__ qn, S* __restrict__ kn, S* __restrict__ v)
{
    const int r0 = blockIdx.x * ROWS;     // flat token row (b*N + n)
    const int t = threadIdx.x;            // output channel
    __shared__ float xs[ROWS][C_];
#pragma unroll
    for (int r = 0; r < ROWS; r++) xs[r][t] = x[(size_t)(r0 + r) * C_ + t];
    __syncthreads();

    float aq[ROWS], ak[ROWS], av[ROWS];
    const float bqv = bq[t], bkv0 = bkv[t], bkv1 = bkv[C_ + t];
#pragma unroll
    for (int r = 0; r < ROWS; r++) { aq[r] = bqv; ak[r] = bkv0; av[r] = bkv1; }

    for (int c = 0; c < C_; c++) {
        float wq = Wq[c * C_ + t];
        float wk = Wkv[c * 2 * C_ + t];
        float wv = Wkv[c * 2 * C_ + C_ + t];
#pragma unroll
        for (int r = 0; r < ROWS; r++) {
            float xv = xs[r][c];
            aq[r] += xv * wq;
            ak[r] += xv * wk;
            av[r] += xv * wv;
        }
    }
#pragma unroll
    for (int r = 0; r < ROWS; r++) {
        float nq = fmaxf(sqrtf(half_reduce(aq[r] * aq[r])), 1e-12f);
        float nk = fmaxf(sqrtf(half_reduce(ak[r] * ak[r])), 1e-12f);
        size_t o = (size_t)(r0 + r) * C_ + t;
        stS(qn, o, aq[r] / nq);
        stS(kn, o, ak[r] / nk);
        stS(v,  o, av[r]);
    }
}

// ---------------- kernel B: SR path (conv1x1+GELU -> pool -> LN -> kv -> norm) ----------------
__global__ __launch_bounds__(256) void k_sr(
    const float* __restrict__ x,
    const float* __restrict__ Wsr, const float* __restrict__ bsr,
    const float* __restrict__ Wkv, const float* __restrict__ bkv,
    const float* __restrict__ ln_g, const float* __restrict__ ln_b,
    float* __restrict__ kpn, float* __restrict__ vp)
{
    const int bid = blockIdx.x;           // b*P + p
    const int b = bid / P_, p = bid % P_;
    const int py = p / PH, px = p % PH;
    const int t = threadIdx.x;
    __shared__ float xs[C_];
    __shared__ float xp[C_];
    __shared__ float red[4];

    float acc = 0.f;
    for (int pi = 0; pi < 64; pi++) {
        int iy = pi >> 3, ix = pi & 7;
        int n = (py * 8 + iy) * W_ + (px * 8 + ix);
        __syncthreads();
        xs[t] = x[((size_t)b * N_ + n) * C_ + t];
        __syncthreads();
        float s = bsr[t];
        for (int c = 0; c < C_; c++) s += xs[c] * Wsr[c * C_ + t];
        acc += 0.5f * s * (1.0f + erff(s * 0.70710678118654752f));  // exact GELU
    }
    acc *= (1.0f / 64.0f);

    // LayerNorm over the 256 channels
    float mean = block_sum(acc, red) * (1.0f / C_);
    float dv = acc - mean;
    float var = block_sum(dv * dv, red) * (1.0f / C_);
    float xpv = dv * rsqrtf(var + 1e-5f) * ln_g[t] + ln_b[t];
    xp[t] = xpv;
    __syncthreads();

    float ak = bkv[t];
    float av = bkv[C_ + t];
    for (int c = 0; c < C_; c++) {
        float xv = xp[c];
        ak += xv * Wkv[c * 2 * C_ + t];
        av += xv * Wkv[c * 2 * C_ + C_ + t];
    }
    float nk = fmaxf(sqrtf(half_reduce(ak * ak)), 1e-12f);
    size_t o = (size_t)bid * C_ + t;
    kpn[o] = ak / nk;
    vp[o]  = av;
}

// ---------------- kernel C: logits + softmax + weighted sums -> pre ----------------
template <typename S>
__global__ __launch_bounds__(256) void k_attn(
    const S* __restrict__ qn, const S* __restrict__ kn, const S* __restrict__ v,
    const float* __restrict__ kpn, const float* __restrict__ vp,
    const float* __restrict__ tok1, const float* __restrict__ bias1,
    const float* __restrict__ tok2, const float* __restrict__ bias2,
    S* __restrict__ pre)
{
    const int bid = blockIdx.x;           // b*N + n
    const int b = bid / N_, n = bid % N_;
    const int y = n / W_, xx = n % W_;
    const int t = threadIdx.x;
    const int head = t >> 5, dd = t & 31;

    __shared__ float wgt[NH][84];         // logits -> softmax weights (83 used)
    __shared__ float tokc[NH][36];        // q.tok + bias (34 used)

    const float qv = ldS(qn, (size_t)bid * C_ + t);

    // 3x3 local logits + token coefficients
#pragma unroll
    for (int l = 0; l < 9; l++) {
        int yy = y + l / 3 - 1, x2 = xx + l % 3 - 1;
        bool in = (yy >= 0) && (yy < H_) && (x2 >= 0) && (x2 < W_);
        float kv = in ? ldS(kn, ((size_t)b * N_ + yy * W_ + x2) * C_ + t) : 0.f;
        float a  = half_reduce(qv * kv);
        float tk = half_reduce(qv * tok1[(head * HD + dd) * 9 + l]);
        if (dd == 0) {
            wgt[head][l]  = in ? a : -INFINITY;
            tokc[head][l] = tk + bias1[head * 9 + l];
        }
    }
    // 5x5 local logits + token coefficients
    for (int l = 0; l < 25; l++) {
        int yy = y + l / 5 - 2, x2 = xx + l % 5 - 2;
        bool in = (yy >= 0) && (yy < H_) && (x2 >= 0) && (x2 < W_);
        float kv = in ? ldS(kn, ((size_t)b * N_ + yy * W_ + x2) * C_ + t) : 0.f;
        float a  = half_reduce(qv * kv);
        float tk = half_reduce(qv * tok2[(head * HD + dd) * 25 + l]);
        if (dd == 0) {
            wgt[head][9 + l]  = in ? a : -INFINITY;
            tokc[head][9 + l] = tk + bias2[head * 25 + l];
        }
    }
    // pooled logits
    for (int p = 0; p < P_; p++) {
        float a = half_reduce(qv * kpn[((size_t)b * P_ + p) * C_ + t]);
        if (dd == 0) wgt[head][34 + p] = a;
    }
    __syncthreads();

    // softmax over 83 entries, 32 lanes per head (each lane handles up to 3)
    float v0 = wgt[head][dd];
    float v1 = wgt[head][dd + 32];
    float v2 = (dd < 19) ? wgt[head][dd + 64] : -INFINITY;
    float mx = fmaxf(v0, fmaxf(v1, v2));
#pragma unroll
    for (int m = 16; m >= 1; m >>= 1) mx = fmaxf(mx, __shfl_xor(mx, m));
    float e0 = expf(v0 - mx);
    float e1 = expf(v1 - mx);
    float e2 = (dd < 19) ? expf(v2 - mx) : 0.f;
    float s  = half_reduce(e0 + e1 + e2);
    float inv = 1.0f / s;
    wgt[head][dd]      = e0 * inv;
    wgt[head][dd + 32] = e1 * inv;
    if (dd < 19) wgt[head][dd + 64] = e2 * inv;
    __syncthreads();

    // weighted sums: local 3x3, local 5x5 (zero-padded v), pooled
    float acc = 0.f;
#pragma unroll
    for (int l = 0; l < 9; l++) {
        int yy = y + l / 3 - 1, x2 = xx + l % 3 - 1;
        bool in = (yy >= 0) && (yy < H_) && (x2 >= 0) && (x2 < W_);
        float vv = in ? ldS(v, ((size_t)b * N_ + yy * W_ + x2) * C_ + t) : 0.f;
        acc += (tokc[head][l] + wgt[head][l]) * vv;
    }
    for (int l = 0; l < 25; l++) {
        int yy = y + l / 5 - 2, x2 = xx + l % 5 - 2;
        bool in = (yy >= 0) && (yy < H_) && (x2 >= 0) && (x2 < W_);
        float vv = in ? ldS(v, ((size_t)b * N_ + yy * W_ + x2) * C_ + t) : 0.f;
        acc += (tokc[head][9 + l] + wgt[head][9 + l]) * vv;
    }
    for (int p = 0; p < P_; p++) {
        acc += wgt[head][34 + p] * vp[((size_t)b * P_ + p) * C_ + t];
    }
    stS(pre, (size_t)bid * C_ + t, acc);
}

// ---------------- kernel D: output projection (8 rows/block) ----------------
template <typename S>
__global__ __launch_bounds__(256) void k_proj(
    const S* __restrict__ pre,
    const float* __restrict__ Wproj, const float* __restrict__ bproj,
    float* __restrict__ out)
{
    const int r0 = blockIdx.x * ROWS;
    const int t = threadIdx.x;
    __shared__ float ps[ROWS][C_];
#pragma unroll
    for (int r = 0; r < ROWS; r++) ps[r][t] = ldS(pre, (size_t)(r0 + r) * C_ + t);
    __syncthreads();

    float o[ROWS];
    const float bp = bproj[t];
#pragma unroll
    for (int r = 0; r < ROWS; r++) o[r] = bp;
    for (int c = 0; c < C_; c++) {
        float w = Wproj[c * C_ + t];
#pragma unroll
        for (int r = 0; r < ROWS; r++) o[r] += ps[r][c] * w;
    }
#pragma unroll
    for (int r = 0; r < ROWS; r++) out[(size_t)(r0 + r) * C_ + t] = o[r];
}

template <typename S>
static void launch_all(const float* x, const float* Wq, const float* bq,
                       const float* Wkv, const float* bkv,
                       const float* Wsr, const float* bsr,
                       const float* ln_g, const float* ln_b,
                       const float* tok1, const float* bias1,
                       const float* tok2, const float* bias2,
                       const float* Wproj, const float* bproj,
                       float* out, void* d_ws, hipStream_t stream)
{
    const size_t big = (size_t)B_ * N_ * C_;
    S* qn  = (S*)d_ws;
    S* kn  = qn + big;
    S* v   = kn + big;
    S* pre = v + big;
    float* kpn = (float*)(pre + big);
    float* vp  = kpn + (size_t)B_ * P_ * C_;

    k_qkv<S><<<B_ * N_ / ROWS, 256, 0, stream>>>(x, Wq, bq, Wkv, bkv, qn, kn, v);
    k_sr<<<B_ * P_, 256, 0, stream>>>(x, Wsr, bsr, Wkv, bkv, ln_g, ln_b, kpn, vp);
    k_attn<S><<<B_ * N_, 256, 0, stream>>>(qn, kn, v, kpn, vp,
                                           tok1, bias1, tok2, bias2, pre);
    k_proj<S><<<B_ * N_ / ROWS, 256, 0, stream>>>(pre, Wproj, bproj, out);
}

extern "C" void kernel_launch(void* const* d_in, const int* in_sizes, int n_in,
                              void* d_out, int out_size, void* d_ws, size_t ws_size,
                              hipStream_t stream)
{
    (void)in_sizes; (void)n_in; (void)out_size;
    const float* x     = (const float*)d_in[0];
    const float* Wq    = (const float*)d_in[1];
    const float* bq    = (const float*)d_in[2];
    const float* Wkv   = (const float*)d_in[3];
    const float* bkv   = (const float*)d_in[4];
    const float* Wsr   = (const float*)d_in[5];
    const float* bsr   = (const float*)d_in[6];
    const float* ln_g  = (const float*)d_in[7];
    const float* ln_b  = (const float*)d_in[8];
    const float* tok1  = (const float*)d_in[9];
    const float* bias1 = (const float*)d_in[10];
    const float* tok2  = (const float*)d_in[11];
    const float* bias2 = (const float*)d_in[12];
    const float* Wproj = (const float*)d_in[13];
    const float* bproj = (const float*)d_in[14];
    float* out = (float*)d_out;

    const size_t big = (size_t)B_ * N_ * C_;
    const size_t small = (size_t)B_ * P_ * C_;
    const size_t need_f32 = 4 * big * sizeof(float) + 2 * small * sizeof(float);

    if (ws_size >= need_f32) {
        launch_all<float>(x, Wq, bq, Wkv, bkv, Wsr, bsr, ln_g, ln_b,
                          tok1, bias1, tok2, bias2, Wproj, bproj, out, d_ws, stream);
    } else {
        launch_all<bf16>(x, Wq, bq, Wkv, bkv, Wsr, bsr, ln_g, ln_b,
                         tok1, bias1, tok2, bias2, Wproj, bproj, out, d_ws, stream);
    }
}

// Round 3
// 551.563 us; speedup vs baseline: 1.5727x; 1.5727x over previous
//
#include <hip/hip_runtime.h>
#include <hip/hip_bf16.h>

using bf16 = __hip_bfloat16;

#define B_  4
#define H_  56
#define W_  56
#define N_  3136
#define C_  256
#define NH  8
#define HD  32
#define P_  49
#define PH  7
#define ROWS 8

__device__ __forceinline__ float ldS(const float* p, size_t i) { return p[i]; }
__device__ __forceinline__ float ldS(const bf16*  p, size_t i) { return __bfloat162float(p[i]); }
__device__ __forceinline__ void  stS(float* p, size_t i, float v) { p[i] = v; }
__device__ __forceinline__ void  stS(bf16*  p, size_t i, float v) { p[i] = __float2bfloat16(v); }

// butterfly sum over each 32-lane half of a 64-lane wave
__device__ __forceinline__ float half_reduce(float v) {
#pragma unroll
    for (int m = 16; m >= 1; m >>= 1) v += __shfl_xor(v, m);
    return v;
}

// block (256 threads) sum; red must be float[4] shared
__device__ __forceinline__ float block_sum(float val, float* red) {
#pragma unroll
    for (int m = 32; m >= 1; m >>= 1) val += __shfl_xor(val, m);
    __syncthreads();
    if ((threadIdx.x & 63) == 0) red[threadIdx.x >> 6] = val;
    __syncthreads();
    return red[0] + red[1] + red[2] + red[3];
}

// ---------------- kernel A: q/k/v projection + per-head normalize (8 rows/block) ----------------
template <typename S>
__global__ __launch_bounds__(256) void k_qkv(
    const float* __restrict__ x,
    const float* __restrict__ Wq, const float* __restrict__ bq,
    const float* __restrict__ Wkv, const float* __restrict__ bkv,
    S* __restrict__ qn, S* __restrict__ kn, S* __restrict__ v)
{
    const int r0 = blockIdx.x * ROWS;     // flat token row (b*N + n)
    const int t = threadIdx.x;            // output channel
    __shared__ float xs[ROWS][C_];
#pragma unroll
    for (int r = 0; r < ROWS; r++) xs[r][t] = x[(size_t)(r0 + r) * C_ + t];
    __syncthreads();

    float aq[ROWS], ak[ROWS], av[ROWS];
    const float bqv = bq[t], bkv0 = bkv[t], bkv1 = bkv[C_ + t];
#pragma unroll
    for (int r = 0; r < ROWS; r++) { aq[r] = bqv; ak[r] = bkv0; av[r] = bkv1; }

    for (int c = 0; c < C_; c++) {
        float wq = Wq[c * C_ + t];
        float wk = Wkv[c * 2 * C_ + t];
        float wv = Wkv[c * 2 * C_ + C_ + t];
#pragma unroll
        for (int r = 0; r < ROWS; r++) {
            float xv = xs[r][c];
            aq[r] += xv * wq;
            ak[r] += xv * wk;
            av[r] += xv * wv;
        }
    }
#pragma unroll
    for (int r = 0; r < ROWS; r++) {
        float nq = fmaxf(sqrtf(half_reduce(aq[r] * aq[r])), 1e-12f);
        float nk = fmaxf(sqrtf(half_reduce(ak[r] * ak[r])), 1e-12f);
        size_t o = (size_t)(r0 + r) * C_ + t;
        stS(qn, o, aq[r] / nq);
        stS(kn, o, ak[r] / nk);
        stS(v,  o, av[r]);
    }
}

// ---------------- kernel B1: SR conv1x1+GELU partial pooled sums (8 px/block) ----------------
__global__ __launch_bounds__(256) void k_sr1(
    const float* __restrict__ x,
    const float* __restrict__ Wsr, const float* __restrict__ bsr,
    float* __restrict__ srpart)
{
    const int cell = blockIdx.x >> 3;     // b*P + p
    const int g = blockIdx.x & 7;         // pixel group (8 pixels each)
    const int b = cell / P_, p = cell % P_;
    const int py = p / PH, px = p % PH;
    const int t = threadIdx.x;
    __shared__ float xs[C_];

    float acc = 0.f;
    for (int k = 0; k < 8; k++) {
        int pi = g * 8 + k;
        int iy = pi >> 3, ix = pi & 7;
        int n = (py * 8 + iy) * W_ + (px * 8 + ix);
        __syncthreads();
        xs[t] = x[((size_t)b * N_ + n) * C_ + t];
        __syncthreads();
        float s = bsr[t];
        for (int c = 0; c < C_; c++) s += xs[c] * Wsr[c * C_ + t];
        acc += 0.5f * s * (1.0f + erff(s * 0.70710678118654752f));  // exact GELU
    }
    srpart[((size_t)cell * 8 + g) * C_ + t] = acc;
}

// ---------------- kernel B2: pool + LN + kv proj + normalize ----------------
__global__ __launch_bounds__(256) void k_sr2(
    const float* __restrict__ srpart,
    const float* __restrict__ Wkv, const float* __restrict__ bkv,
    const float* __restrict__ ln_g, const float* __restrict__ ln_b,
    float* __restrict__ kpn, float* __restrict__ vp)
{
    const int cell = blockIdx.x;          // b*P + p
    const int t = threadIdx.x;
    __shared__ float xp[C_];
    __shared__ float red[4];

    float acc = 0.f;
#pragma unroll
    for (int g = 0; g < 8; g++) acc += srpart[((size_t)cell * 8 + g) * C_ + t];
    acc *= (1.0f / 64.0f);

    float mean = block_sum(acc, red) * (1.0f / C_);
    float dv = acc - mean;
    float var = block_sum(dv * dv, red) * (1.0f / C_);
    float xpv = dv * rsqrtf(var + 1e-5f) * ln_g[t] + ln_b[t];
    xp[t] = xpv;
    __syncthreads();

    float ak = bkv[t];
    float av = bkv[C_ + t];
    for (int c = 0; c < C_; c++) {
        float xv = xp[c];
        ak += xv * Wkv[c * 2 * C_ + t];
        av += xv * Wkv[c * 2 * C_ + C_ + t];
    }
    float nk = fmaxf(sqrtf(half_reduce(ak * ak)), 1e-12f);
    size_t o = (size_t)cell * C_ + t;
    kpn[o] = ak / nk;
    vp[o]  = av;
}

// ---------------- kernel C: lane-per-logit + softmax + weighted sums -> pre ----------------
template <typename S>
__global__ __launch_bounds__(256) void k_attn(
    const S* __restrict__ qn, const S* __restrict__ kn, const S* __restrict__ v,
    const float* __restrict__ kpn, const float* __restrict__ vp,
    const float* __restrict__ tok1, const float* __restrict__ bias1,
    const float* __restrict__ tok2, const float* __restrict__ bias2,
    S* __restrict__ pre)
{
    const int bid = blockIdx.x;           // b*N + n
    const int b = bid / N_, n = bid % N_;
    const int y = n / W_, xx = n % W_;
    const int t = threadIdx.x;
    const int head = t >> 5, dd = t & 31;

    __shared__ float wgt[NH][84];         // logits -> softmax weights (83 used)
    __shared__ float tokc[NH][36];        // q.tok + bias (34 used)

    // ---- phase 1: lane-per-logit dots (8 heads x 83 keys = 664 items) ----
    for (int item = t; item < NH * 83; item += 256) {
        const int hh = item & 7;
        const int l = item >> 3;
        // q fragment for this head (32 floats, 128B aligned)
        float qf[32];
        {
            const S* qrow = qn + (size_t)bid * C_ + hh * HD;
#pragma unroll
            for (int d = 0; d < 32; d++) qf[d] = ldS(qrow, d);
        }
        if (l < 34) {
            // local window logit + token coefficient
            int yy, x2;
            if (l < 9) { yy = y + l / 3 - 1; x2 = xx + l % 3 - 1; }
            else { int li = l - 9; yy = y + li / 5 - 2; x2 = xx + li % 5 - 2; }
            bool in = (yy >= 0) && (yy < H_) && (x2 >= 0) && (x2 < W_);
            float a = 0.f;
            if (in) {
                const S* krow = kn + ((size_t)b * N_ + yy * W_ + x2) * C_ + hh * HD;
#pragma unroll
                for (int d = 0; d < 32; d++) a += qf[d] * ldS(krow, d);
            }
            float tk;
            if (l < 9) {
                tk = bias1[hh * 9 + l];
#pragma unroll
                for (int d = 0; d < 32; d++) tk += qf[d] * tok1[(hh * HD + d) * 9 + l];
            } else {
                int li = l - 9;
                tk = bias2[hh * 25 + li];
#pragma unroll
                for (int d = 0; d < 32; d++) tk += qf[d] * tok2[(hh * HD + d) * 25 + li];
            }
            wgt[hh][l] = in ? a : -INFINITY;
            tokc[hh][l] = tk;
        } else {
            int p = l - 34;
            const float* krow = kpn + ((size_t)b * P_ + p) * C_ + hh * HD;
            float a = 0.f;
#pragma unroll
            for (int d = 0; d < 32; d++) a += qf[d] * krow[d];
            wgt[hh][l] = a;
        }
    }
    __syncthreads();

    // ---- phase 2: softmax over 83 entries, 32 lanes per head ----
    float v0 = wgt[head][dd];
    float v1 = wgt[head][dd + 32];
    float v2 = (dd < 19) ? wgt[head][dd + 64] : -INFINITY;
    float mx = fmaxf(v0, fmaxf(v1, v2));
#pragma unroll
    for (int m = 16; m >= 1; m >>= 1) mx = fmaxf(mx, __shfl_xor(mx, m));
    float e0 = expf(v0 - mx);
    float e1 = expf(v1 - mx);
    float e2 = (dd < 19) ? expf(v2 - mx) : 0.f;
    float s  = half_reduce(e0 + e1 + e2);
    float inv = 1.0f / s;
    wgt[head][dd]      = e0 * inv;
    wgt[head][dd + 32] = e1 * inv;
    if (dd < 19) wgt[head][dd + 64] = e2 * inv;
    __syncthreads();

    // ---- phase 3: weighted sums: local 3x3, local 5x5 (zero-padded v), pooled ----
    float acc = 0.f;
#pragma unroll
    for (int l = 0; l < 9; l++) {
        int yy = y + l / 3 - 1, x2 = xx + l % 3 - 1;
        bool in = (yy >= 0) && (yy < H_) && (x2 >= 0) && (x2 < W_);
        float vv = in ? ldS(v, ((size_t)b * N_ + yy * W_ + x2) * C_ + t) : 0.f;
        acc += (tokc[head][l] + wgt[head][l]) * vv;
    }
#pragma unroll 5
    for (int l = 0; l < 25; l++) {
        int yy = y + l / 5 - 2, x2 = xx + l % 5 - 2;
        bool in = (yy >= 0) && (yy < H_) && (x2 >= 0) && (x2 < W_);
        float vv = in ? ldS(v, ((size_t)b * N_ + yy * W_ + x2) * C_ + t) : 0.f;
        acc += (tokc[head][9 + l] + wgt[head][9 + l]) * vv;
    }
#pragma unroll 7
    for (int p = 0; p < P_; p++) {
        acc += wgt[head][34 + p] * vp[((size_t)b * P_ + p) * C_ + t];
    }
    stS(pre, (size_t)bid * C_ + t, acc);
}

// ---------------- kernel D: output projection (8 rows/block) ----------------
template <typename S>
__global__ __launch_bounds__(256) void k_proj(
    const S* __restrict__ pre,
    const float* __restrict__ Wproj, const float* __restrict__ bproj,
    float* __restrict__ out)
{
    const int r0 = blockIdx.x * ROWS;
    const int t = threadIdx.x;
    __shared__ float ps[ROWS][C_];
#pragma unroll
    for (int r = 0; r < ROWS; r++) ps[r][t] = ldS(pre, (size_t)(r0 + r) * C_ + t);
    __syncthreads();

    float o[ROWS];
    const float bp = bproj[t];
#pragma unroll
    for (int r = 0; r < ROWS; r++) o[r] = bp;
    for (int c = 0; c < C_; c++) {
        float w = Wproj[c * C_ + t];
#pragma unroll
        for (int r = 0; r < ROWS; r++) o[r] += ps[r][c] * w;
    }
#pragma unroll
    for (int r = 0; r < ROWS; r++) out[(size_t)(r0 + r) * C_ + t] = o[r];
}

template <typename S>
static void launch_all(const float* x, const float* Wq, const float* bq,
                       const float* Wkv, const float* bkv,
                       const float* Wsr, const float* bsr,
                       const float* ln_g, const float* ln_b,
                       const float* tok1, const float* bias1,
                       const float* tok2, const float* bias2,
                       const float* Wproj, const float* bproj,
                       float* out, void* d_ws, hipStream_t stream)
{
    const size_t big = (size_t)B_ * N_ * C_;
    const size_t small = (size_t)B_ * P_ * C_;
    S* qn  = (S*)d_ws;
    S* kn  = qn + big;
    S* v   = kn + big;
    S* pre = v + big;
    float* kpn    = (float*)(pre + big);
    float* vp     = kpn + small;
    float* srpart = vp + small;           // B*P*8*C floats

    k_qkv<S><<<B_ * N_ / ROWS, 256, 0, stream>>>(x, Wq, bq, Wkv, bkv, qn, kn, v);
    k_sr1<<<B_ * P_ * 8, 256, 0, stream>>>(x, Wsr, bsr, srpart);
    k_sr2<<<B_ * P_, 256, 0, stream>>>(srpart, Wkv, bkv, ln_g, ln_b, kpn, vp);
    k_attn<S><<<B_ * N_, 256, 0, stream>>>(qn, kn, v, kpn, vp,
                                           tok1, bias1, tok2, bias2, pre);
    k_proj<S><<<B_ * N_ / ROWS, 256, 0, stream>>>(pre, Wproj, bproj, out);
}

extern "C" void kernel_launch(void* const* d_in, const int* in_sizes, int n_in,
                              void* d_out, int out_size, void* d_ws, size_t ws_size,
                              hipStream_t stream)
{
    (void)in_sizes; (void)n_in; (void)out_size;
    const float* x     = (const float*)d_in[0];
    const float* Wq    = (const float*)d_in[1];
    const float* bq    = (const float*)d_in[2];
    const float* Wkv   = (const float*)d_in[3];
    const float* bkv   = (const float*)d_in[4];
    const float* Wsr   = (const float*)d_in[5];
    const float* bsr   = (const float*)d_in[6];
    const float* ln_g  = (const float*)d_in[7];
    const float* ln_b  = (const float*)d_in[8];
    const float* tok1  = (const float*)d_in[9];
    const float* bias1 = (const float*)d_in[10];
    const float* tok2  = (const float*)d_in[11];
    const float* bias2 = (const float*)d_in[12];
    const float* Wproj = (const float*)d_in[13];
    const float* bproj = (const float*)d_in[14];
    float* out = (float*)d_out;

    const size_t big = (size_t)B_ * N_ * C_;
    const size_t small = (size_t)B_ * P_ * C_;
    const size_t srp = (size_t)B_ * P_ * 8 * C_;
    const size_t need_f32 = 4 * big * sizeof(float) + (2 * small + srp) * sizeof(float);

    if (ws_size >= need_f32) {
        launch_all<float>(x, Wq, bq, Wkv, bkv, Wsr, bsr, ln_g, ln_b,
                          tok1, bias1, tok2, bias2, Wproj, bproj, out, d_ws, stream);
    } else {
        launch_all<bf16>(x, Wq, bq, Wkv, bkv, Wsr, bsr, ln_g, ln_b,
                         tok1, bias1, tok2, bias2, Wproj, bproj, out, d_ws, stream);
    }
}

// Round 4
// 490.320 us; speedup vs baseline: 1.7691x; 1.1249x over previous
//
#include <hip/hip_runtime.h>
#include <hip/hip_bf16.h>

using bf16 = __hip_bfloat16;

#define B_  4
#define H_  56
#define W_  56
#define N_  3136
#define C_  256
#define NH  8
#define HD  32
#define P_  49
#define PH  7
#define ROWS 8
#define SD  132          // LDS row stride (dwords) for swizzled bf16-pair tiles (132%32==4)
#define TOKC 272         // 8 heads * 34 token coefficients

// butterfly sum over each 32-lane half of a 64-lane wave
__device__ __forceinline__ float half_reduce(float v) {
#pragma unroll
    for (int m = 16; m >= 1; m >>= 1) v += __shfl_xor(v, m);
    return v;
}

// block (256 threads) sum; red must be float[4] shared
__device__ __forceinline__ float block_sum(float val, float* red) {
#pragma unroll
    for (int m = 32; m >= 1; m >>= 1) val += __shfl_xor(val, m);
    __syncthreads();
    if ((threadIdx.x & 63) == 0) red[threadIdx.x >> 6] = val;
    __syncthreads();
    return red[0] + red[1] + red[2] + red[3];
}

// dot of q (8x float4) with a swizzled bf16-pair LDS row segment for head h2
__device__ __forceinline__ float dot32(const uint32_t* row, const float4* qf, int h2) {
    float a = 0.f;
#pragma unroll
    for (int jp = 0; jp < 8; jp++) {
        int pc = (2 * jp + 2 * h2) & 15;
        uint2 w = *reinterpret_cast<const uint2*>(row + pc);
        float4 q = qf[jp];
        a += q.x * __uint_as_float(w.x << 16);
        a += q.y * __uint_as_float(w.x & 0xffff0000u);
        a += q.z * __uint_as_float(w.y << 16);
        a += q.w * __uint_as_float(w.y & 0xffff0000u);
    }
    return a;
}

// ---------------- kernel A: q/k/v projection + normalize + tokc precompute ----------------
__global__ __launch_bounds__(256) void k_qkv(
    const float* __restrict__ x,
    const float* __restrict__ Wq, const float* __restrict__ bq,
    const float* __restrict__ Wkv, const float* __restrict__ bkv,
    const float* __restrict__ tok1, const float* __restrict__ bias1,
    const float* __restrict__ tok2, const float* __restrict__ bias2,
    float* __restrict__ qn, bf16* __restrict__ kn, float* __restrict__ v,
    float* __restrict__ tokc_g)
{
    const int r0 = blockIdx.x * ROWS;     // flat token row (b*N + n)
    const int t = threadIdx.x;            // output channel
    __shared__ float xs[ROWS][C_ + 1];
    __shared__ float tokL[TOKC * 33];     // [h*34+l][d], stride 33

    // stage tok transposed: tokL[(h*34+l)*33 + d]
    for (int idx = t; idx < TOKC * 32; idx += 256) {
        int hl = idx >> 5, d = idx & 31;
        int h = hl / 34, l = hl % 34;
        float val = (l < 9) ? tok1[(h * HD + d) * 9 + l]
                            : tok2[(h * HD + d) * 25 + (l - 9)];
        tokL[hl * 33 + d] = val;
    }
#pragma unroll
    for (int r = 0; r < ROWS; r++) xs[r][t] = x[(size_t)(r0 + r) * C_ + t];
    __syncthreads();

    float aq[ROWS], ak[ROWS], av[ROWS];
    const float bqv = bq[t], bkv0 = bkv[t], bkv1 = bkv[C_ + t];
#pragma unroll
    for (int r = 0; r < ROWS; r++) { aq[r] = bqv; ak[r] = bkv0; av[r] = bkv1; }

    for (int c = 0; c < C_; c++) {
        float wq = Wq[c * C_ + t];
        float wk = Wkv[c * 2 * C_ + t];
        float wv = Wkv[c * 2 * C_ + C_ + t];
#pragma unroll
        for (int r = 0; r < ROWS; r++) {
            float xv = xs[r][c];
            aq[r] += xv * wq;
            ak[r] += xv * wk;
            av[r] += xv * wv;
        }
    }
    float qv[ROWS];
#pragma unroll
    for (int r = 0; r < ROWS; r++) {
        float nq = fmaxf(sqrtf(half_reduce(aq[r] * aq[r])), 1e-12f);
        float nk = fmaxf(sqrtf(half_reduce(ak[r] * ak[r])), 1e-12f);
        qv[r] = aq[r] / nq;
        size_t o = (size_t)(r0 + r) * C_ + t;
        qn[o] = qv[r];
        kn[o] = __float2bfloat16(ak[r] / nk);
        v[o]  = av[r];
    }
    __syncthreads();
#pragma unroll
    for (int r = 0; r < ROWS; r++) xs[r][t] = qv[r];
    __syncthreads();

    // tokc: 8 rows x 272 coefficients, K=32
    for (int out = t; out < ROWS * TOKC; out += 256) {
        int r = out / TOKC, c = out % TOKC;
        int h = c / 34, l = c % 34;
        float s = (l < 9) ? bias1[h * 9 + l] : bias2[h * 25 + (l - 9)];
        const float* tl = &tokL[c * 33];
        const float* qrow = &xs[r][h * HD];
#pragma unroll
        for (int d = 0; d < 32; d++) s += qrow[d] * tl[d];
        tokc_g[(size_t)(r0 + r) * TOKC + c] = s;
    }
}

// ---------------- kernel B1: SR conv1x1+GELU partial pooled sums (weights-outer) ----------------
__global__ __launch_bounds__(256) void k_sr1(
    const float* __restrict__ x,
    const float* __restrict__ Wsr, const float* __restrict__ bsr,
    float* __restrict__ srpart)
{
    const int cell = blockIdx.x >> 3;     // b*P + p
    const int g = blockIdx.x & 7;         // pixel group (8 pixels)
    const int b = cell / P_, p = cell % P_;
    const int py = p / PH, px = p % PH;
    const int t = threadIdx.x;
    __shared__ float xs[8][C_ + 1];

#pragma unroll
    for (int k = 0; k < 8; k++) {
        int pi = g * 8 + k;
        int iy = pi >> 3, ix = pi & 7;
        int n = (py * 8 + iy) * W_ + (px * 8 + ix);
        xs[k][t] = x[((size_t)b * N_ + n) * C_ + t];
    }
    __syncthreads();

    float s[8];
    const float bs = bsr[t];
#pragma unroll
    for (int k = 0; k < 8; k++) s[k] = bs;
    for (int c = 0; c < C_; c++) {
        float w = Wsr[c * C_ + t];
#pragma unroll
        for (int k = 0; k < 8; k++) s[k] += xs[k][c] * w;
    }
    float acc = 0.f;
#pragma unroll
    for (int k = 0; k < 8; k++)
        acc += 0.5f * s[k] * (1.0f + erff(s[k] * 0.70710678118654752f));
    srpart[((size_t)cell * 8 + g) * C_ + t] = acc;
}

// ---------------- kernel B2: pool + LN + kv proj + normalize ----------------
__global__ __launch_bounds__(256) void k_sr2(
    const float* __restrict__ srpart,
    const float* __restrict__ Wkv, const float* __restrict__ bkv,
    const float* __restrict__ ln_g, const float* __restrict__ ln_b,
    bf16* __restrict__ kpn, float* __restrict__ vp)
{
    const int cell = blockIdx.x;          // b*P + p
    const int t = threadIdx.x;
    __shared__ float xp[C_];
    __shared__ float red[4];

    float acc = 0.f;
#pragma unroll
    for (int g = 0; g < 8; g++) acc += srpart[((size_t)cell * 8 + g) * C_ + t];
    acc *= (1.0f / 64.0f);

    float mean = block_sum(acc, red) * (1.0f / C_);
    float dv = acc - mean;
    float var = block_sum(dv * dv, red) * (1.0f / C_);
    float xpv = dv * rsqrtf(var + 1e-5f) * ln_g[t] + ln_b[t];
    xp[t] = xpv;
    __syncthreads();

    float ak = bkv[t];
    float av = bkv[C_ + t];
    for (int c = 0; c < C_; c++) {
        float xv = xp[c];
        ak += xv * Wkv[c * 2 * C_ + t];
        av += xv * Wkv[c * 2 * C_ + C_ + t];
    }
    float nk = fmaxf(sqrtf(half_reduce(ak * ak)), 1e-12f);
    size_t o = (size_t)cell * C_ + t;
    kpn[o] = __float2bfloat16(ak / nk);
    vp[o]  = av;
}

// ---------------- kernel C: LDS-staged logits + softmax + weighted sums -> pre ----------------
__global__ __launch_bounds__(256) void k_attn(
    const float* __restrict__ qn, const uint32_t* __restrict__ knu,
    const float* __restrict__ v,
    const uint32_t* __restrict__ kpnu, const float* __restrict__ vp,
    const float* __restrict__ tokc_g,
    float* __restrict__ pre)
{
    const int bid = blockIdx.x;           // b*N + n
    const int b = bid / N_, n = bid % N_;
    const int y = n / W_, xx = n % W_;
    const int t = threadIdx.x;
    const int hh = t & 7;                 // head for dot items
    const int hq = t >> 5, dd = t & 31;   // head/lane for softmax & phase3

    __shared__ __align__(16) uint32_t ks_u[25 * SD];
    __shared__ __align__(16) uint32_t kps_u[49 * SD];
    __shared__ float wgt[NH][84];
    __shared__ float tokcS[TOKC];

    // ---- stage 25 k window rows (bf16 pairs, head-rotation swizzle) ----
    for (int idx = t; idx < 25 * 128; idx += 256) {
        int l = idx >> 7, jj = idx & 127;
        int dy = l / 5 - 2, dx = l % 5 - 2;
        int yy = y + dy, x2 = xx + dx;
        bool in = (yy >= 0) && (yy < H_) && (x2 >= 0) && (x2 < W_);
        uint32_t val = in ? knu[((size_t)b * N_ + yy * W_ + x2) * 128 + jj] : 0u;
        int h2 = jj >> 4, j = jj & 15;
        ks_u[l * SD + h2 * 16 + ((j + 2 * h2) & 15)] = val;
    }
    // ---- stage 49 pooled k rows ----
    for (int idx = t; idx < 49 * 128; idx += 256) {
        int p = idx >> 7, jj = idx & 127;
        uint32_t val = kpnu[((size_t)b * P_ + p) * 128 + jj];
        int h2 = jj >> 4, j = jj & 15;
        kps_u[p * SD + h2 * 16 + ((j + 2 * h2) & 15)] = val;
    }
    // ---- stage tokc ----
    tokcS[t] = tokc_g[(size_t)bid * TOKC + t];
    if (t < TOKC - 256) tokcS[256 + t] = tokc_g[(size_t)bid * TOKC + 256 + t];

    // ---- q fragment for head hh ----
    float4 qf[8];
    {
        const float4* qrow = reinterpret_cast<const float4*>(qn + (size_t)bid * C_ + hh * HD);
#pragma unroll
        for (int j = 0; j < 8; j++) qf[j] = qrow[j];
    }
    __syncthreads();

    // ---- window logits: 200 items (25 offsets x 8 heads) ----
    if (t < 200) {
        int l = t >> 3;
        int dy = l / 5 - 2, dx = l % 5 - 2;
        int yy = y + dy, x2 = xx + dx;
        bool in = (yy >= 0) && (yy < H_) && (x2 >= 0) && (x2 < W_);
        float a = -INFINITY;
        if (in) a = dot32(&ks_u[l * SD + hh * 16], qf, hh);
        wgt[hh][9 + l] = a;
    }
    // ---- pooled logits: 392 items ----
    {
        int p = t >> 3;
        wgt[hh][34 + p] = dot32(&kps_u[p * SD + hh * 16], qf, hh);
        if (t < 136) {
            int p2 = 32 + (t >> 3);
            wgt[hh][34 + p2] = dot32(&kps_u[p2 * SD + hh * 16], qf, hh);
        }
    }
    __syncthreads();
    // ---- replicate inner 3x3 logits from 5x5 dots ----
    if (t < 72) {
        int h = t / 9, l9 = t % 9;
        int dy = l9 / 3 - 1, dx = l9 % 3 - 1;
        int l25 = (dy + 2) * 5 + (dx + 2);
        wgt[h][l9] = wgt[h][9 + l25];
    }
    __syncthreads();

    // ---- softmax over 83 entries, 32 lanes per head ----
    float v0 = wgt[hq][dd];
    float v1 = wgt[hq][dd + 32];
    float v2 = (dd < 19) ? wgt[hq][dd + 64] : -INFINITY;
    float mx = fmaxf(v0, fmaxf(v1, v2));
#pragma unroll
    for (int m = 16; m >= 1; m >>= 1) mx = fmaxf(mx, __shfl_xor(mx, m));
    float e0 = expf(v0 - mx);
    float e1 = expf(v1 - mx);
    float e2 = (dd < 19) ? expf(v2 - mx) : 0.f;
    float ssum = half_reduce(e0 + e1 + e2);
    float inv = 1.0f / ssum;
    __syncthreads();
    wgt[hq][dd]      = e0 * inv;
    wgt[hq][dd + 32] = e1 * inv;
    if (dd < 19) wgt[hq][dd + 64] = e2 * inv;
    __syncthreads();

    // ---- weighted sums: 25 merged local offsets + 49 pooled ----
    float acc = 0.f;
#pragma unroll
    for (int l = 0; l < 25; l++) {
        int dy = l / 5 - 2, dx = l % 5 - 2;
        int yy = y + dy, x2 = xx + dx;
        if (yy < 0 || yy >= H_ || x2 < 0 || x2 >= W_) continue;
        float vv = v[((size_t)b * N_ + yy * W_ + x2) * C_ + t];
        float w = wgt[hq][9 + l] + tokcS[hq * 34 + 9 + l];
        if (dy >= -1 && dy <= 1 && dx >= -1 && dx <= 1) {
            int l9 = (dy + 1) * 3 + (dx + 1);
            w += wgt[hq][l9] + tokcS[hq * 34 + l9];
        }
        acc += w * vv;
    }
#pragma unroll 7
    for (int p = 0; p < P_; p++)
        acc += wgt[hq][34 + p] * vp[((size_t)b * P_ + p) * C_ + t];
    pre[(size_t)bid * C_ + t] = acc;
}

// ---------------- kernel D: output projection, in-place on d_out ----------------
__global__ __launch_bounds__(256) void k_proj(
    float* __restrict__ io,
    const float* __restrict__ Wproj, const float* __restrict__ bproj)
{
    const int r0 = blockIdx.x * ROWS;
    const int t = threadIdx.x;
    __shared__ float ps[ROWS][C_ + 1];
#pragma unroll
    for (int r = 0; r < ROWS; r++) ps[r][t] = io[(size_t)(r0 + r) * C_ + t];
    __syncthreads();

    float o[ROWS];
    const float bp = bproj[t];
#pragma unroll
    for (int r = 0; r < ROWS; r++) o[r] = bp;
    for (int c = 0; c < C_; c++) {
        float w = Wproj[c * C_ + t];
#pragma unroll
        for (int r = 0; r < ROWS; r++) o[r] += ps[r][c] * w;
    }
#pragma unroll
    for (int r = 0; r < ROWS; r++) io[(size_t)(r0 + r) * C_ + t] = o[r];
}

extern "C" void kernel_launch(void* const* d_in, const int* in_sizes, int n_in,
                              void* d_out, int out_size, void* d_ws, size_t ws_size,
                              hipStream_t stream)
{
    (void)in_sizes; (void)n_in; (void)out_size; (void)ws_size;
    const float* x     = (const float*)d_in[0];
    const float* Wq    = (const float*)d_in[1];
    const float* bq    = (const float*)d_in[2];
    const float* Wkv   = (const float*)d_in[3];
    const float* bkv   = (const float*)d_in[4];
    const float* Wsr   = (const float*)d_in[5];
    const float* bsr   = (const float*)d_in[6];
    const float* ln_g  = (const float*)d_in[7];
    const float* ln_b  = (const float*)d_in[8];
    const float* tok1  = (const float*)d_in[9];
    const float* bias1 = (const float*)d_in[10];
    const float* tok2  = (const float*)d_in[11];
    const float* bias2 = (const float*)d_in[12];
    const float* Wproj = (const float*)d_in[13];
    const float* bproj = (const float*)d_in[14];
    float* out = (float*)d_out;

    const size_t big   = (size_t)B_ * N_ * C_;     // 3,211,264
    const size_t small = (size_t)B_ * P_ * C_;     // 50,176
    const size_t srp   = (size_t)B_ * P_ * 8 * C_; // 401,408
    const size_t tokn  = (size_t)B_ * N_ * TOKC;   // 3,411,968

    float* qn     = (float*)d_ws;
    float* v      = qn + big;
    float* tokc   = v + big;
    float* vp     = tokc + tokn;
    float* srpart = vp + small;
    bf16*  kn     = (bf16*)(srpart + srp);
    bf16*  kpn    = kn + big;

    k_qkv<<<B_ * N_ / ROWS, 256, 0, stream>>>(x, Wq, bq, Wkv, bkv,
                                              tok1, bias1, tok2, bias2,
                                              qn, kn, v, tokc);
    k_sr1<<<B_ * P_ * 8, 256, 0, stream>>>(x, Wsr, bsr, srpart);
    k_sr2<<<B_ * P_, 256, 0, stream>>>(srpart, Wkv, bkv, ln_g, ln_b, kpn, vp);
    k_attn<<<B_ * N_, 256, 0, stream>>>(qn, (const uint32_t*)kn, v,
                                        (const uint32_t*)kpn, vp, tokc, out);
    k_proj<<<B_ * N_ / ROWS, 256, 0, stream>>>(out, Wproj, bproj);
}

// Round 5
// 343.599 us; speedup vs baseline: 2.5246x; 1.4270x over previous
//
#include <hip/hip_runtime.h>
#include <hip/hip_bf16.h>

using bf16 = __hip_bfloat16;

#define B_  4
#define H_  56
#define W_  56
#define N_  3136
#define C_  256
#define NH  8
#define HD  32
#define P_  49
#define PH  7
#define ROWS 8
#define SD  132          // LDS row stride (dwords) for swizzled bf16-pair rows
#define TOKC 272         // 8 heads * 34 token coefficients
#define ZSTR 528         // Z record stride (dwords): 256 qn + 272 tokc; coef overwrites [0..303]
#define PLSTR 52         // plog stride (ushorts) per (token,head)

__device__ __forceinline__ float bfu2f(ushort u) { return __uint_as_float((uint32_t)u << 16); }
__device__ __forceinline__ ushort f2bf_u(float f) {
    uint32_t u = __float_as_uint(f);
    uint32_t r = (u + 0x7FFFu + ((u >> 16) & 1u)) >> 16;
    return (ushort)r;
}

// butterfly sum over each 32-lane half of a 64-lane wave
__device__ __forceinline__ float half_reduce(float v) {
#pragma unroll
    for (int m = 16; m >= 1; m >>= 1) v += __shfl_xor(v, m);
    return v;
}

// block (256 threads) sum; red must be float[4] shared
__device__ __forceinline__ float block_sum(float val, float* red) {
#pragma unroll
    for (int m = 32; m >= 1; m >>= 1) val += __shfl_xor(val, m);
    __syncthreads();
    if ((threadIdx.x & 63) == 0) red[threadIdx.x >> 6] = val;
    __syncthreads();
    return red[0] + red[1] + red[2] + red[3];
}

// dot of q (8x float4) with a swizzled bf16-pair LDS row segment for head h2
__device__ __forceinline__ float dot32(const uint32_t* row, const float4* qf, int h2) {
    float a = 0.f;
#pragma unroll
    for (int jp = 0; jp < 8; jp++) {
        int pc = (2 * jp + 2 * h2) & 15;
        uint2 w = *reinterpret_cast<const uint2*>(row + pc);
        float4 q = qf[jp];
        a += q.x * __uint_as_float(w.x << 16);
        a += q.y * __uint_as_float(w.x & 0xffff0000u);
        a += q.z * __uint_as_float(w.y << 16);
        a += q.w * __uint_as_float(w.y & 0xffff0000u);
    }
    return a;
}

// ---------------- kernel A: q/k/v projection + normalize + tokc precompute ----------------
__global__ __launch_bounds__(256) void k_qkv(
    const float* __restrict__ x,
    const float* __restrict__ Wq, const float* __restrict__ bq,
    const float* __restrict__ Wkv, const float* __restrict__ bkv,
    const float* __restrict__ tok1, const float* __restrict__ bias1,
    const float* __restrict__ tok2, const float* __restrict__ bias2,
    float* __restrict__ Z, ushort* __restrict__ kn_u, ushort* __restrict__ v_u)
{
    const int r0 = blockIdx.x * ROWS;     // flat token row (b*N + n)
    const int t = threadIdx.x;            // output channel
    __shared__ float xs[ROWS][C_ + 1];
    __shared__ float tokL[TOKC * 33];     // [h*34+l][d], stride 33

    for (int idx = t; idx < TOKC * 32; idx += 256) {
        int hl = idx >> 5, d = idx & 31;
        int h = hl / 34, l = hl % 34;
        float val = (l < 9) ? tok1[(h * HD + d) * 9 + l]
                            : tok2[(h * HD + d) * 25 + (l - 9)];
        tokL[hl * 33 + d] = val;
    }
#pragma unroll
    for (int r = 0; r < ROWS; r++) xs[r][t] = x[(size_t)(r0 + r) * C_ + t];
    __syncthreads();

    float aq[ROWS], ak[ROWS], av[ROWS];
    const float bqv = bq[t], bkv0 = bkv[t], bkv1 = bkv[C_ + t];
#pragma unroll
    for (int r = 0; r < ROWS; r++) { aq[r] = bqv; ak[r] = bkv0; av[r] = bkv1; }

    for (int c = 0; c < C_; c++) {
        float wq = Wq[c * C_ + t];
        float wk = Wkv[c * 2 * C_ + t];
        float wv = Wkv[c * 2 * C_ + C_ + t];
#pragma unroll
        for (int r = 0; r < ROWS; r++) {
            float xv = xs[r][c];
            aq[r] += xv * wq;
            ak[r] += xv * wk;
            av[r] += xv * wv;
        }
    }
    float qv[ROWS];
#pragma unroll
    for (int r = 0; r < ROWS; r++) {
        float nq = fmaxf(sqrtf(half_reduce(aq[r] * aq[r])), 1e-12f);
        float nk = fmaxf(sqrtf(half_reduce(ak[r] * ak[r])), 1e-12f);
        qv[r] = aq[r] / nq;
        size_t o = (size_t)(r0 + r) * C_ + t;
        Z[(size_t)(r0 + r) * ZSTR + t] = qv[r];
        kn_u[o] = f2bf_u(ak[r] / nk);
        v_u[o]  = f2bf_u(av[r]);
    }
    __syncthreads();
#pragma unroll
    for (int r = 0; r < ROWS; r++) xs[r][t] = qv[r];
    __syncthreads();

    // tokc: 8 rows x 272 coefficients, K=32
    for (int out = t; out < ROWS * TOKC; out += 256) {
        int r = out / TOKC, c = out % TOKC;
        int h = c / 34, l = c % 34;
        float s = (l < 9) ? bias1[h * 9 + l] : bias2[h * 25 + (l - 9)];
        const float* tl = &tokL[c * 33];
        const float* qrow = &xs[r][h * HD];
#pragma unroll
        for (int d = 0; d < 32; d++) s += qrow[d] * tl[d];
        Z[(size_t)(r0 + r) * ZSTR + 256 + c] = s;
    }
}

// ---------------- kernel B1: SR conv1x1+GELU partial pooled sums ----------------
__global__ __launch_bounds__(256) void k_sr1(
    const float* __restrict__ x,
    const float* __restrict__ Wsr, const float* __restrict__ bsr,
    float* __restrict__ srpart)
{
    const int cell = blockIdx.x >> 3;     // b*P + p
    const int g = blockIdx.x & 7;         // pixel group (8 pixels)
    const int b = cell / P_, p = cell % P_;
    const int py = p / PH, px = p % PH;
    const int t = threadIdx.x;
    __shared__ float xs[8][C_ + 1];

#pragma unroll
    for (int k = 0; k < 8; k++) {
        int pi = g * 8 + k;
        int iy = pi >> 3, ix = pi & 7;
        int n = (py * 8 + iy) * W_ + (px * 8 + ix);
        xs[k][t] = x[((size_t)b * N_ + n) * C_ + t];
    }
    __syncthreads();

    float s[8];
    const float bs = bsr[t];
#pragma unroll
    for (int k = 0; k < 8; k++) s[k] = bs;
    for (int c = 0; c < C_; c++) {
        float w = Wsr[c * C_ + t];
#pragma unroll
        for (int k = 0; k < 8; k++) s[k] += xs[k][c] * w;
    }
    float acc = 0.f;
#pragma unroll
    for (int k = 0; k < 8; k++)
        acc += 0.5f * s[k] * (1.0f + erff(s[k] * 0.70710678118654752f));
    srpart[((size_t)cell * 8 + g) * C_ + t] = acc;
}

// ---------------- kernel B2: pool + LN + kv proj + normalize ----------------
__global__ __launch_bounds__(256) void k_sr2(
    const float* __restrict__ srpart,
    const float* __restrict__ Wkv, const float* __restrict__ bkv,
    const float* __restrict__ ln_g, const float* __restrict__ ln_b,
    ushort* __restrict__ kpn_u, float* __restrict__ vp)
{
    const int cell = blockIdx.x;          // b*P + p
    const int t = threadIdx.x;
    __shared__ float xp[C_];
    __shared__ float red[4];

    float acc = 0.f;
#pragma unroll
    for (int g = 0; g < 8; g++) acc += srpart[((size_t)cell * 8 + g) * C_ + t];
    acc *= (1.0f / 64.0f);

    float mean = block_sum(acc, red) * (1.0f / C_);
    float dv = acc - mean;
    float var = block_sum(dv * dv, red) * (1.0f / C_);
    float xpv = dv * rsqrtf(var + 1e-5f) * ln_g[t] + ln_b[t];
    xp[t] = xpv;
    __syncthreads();

    float ak = bkv[t];
    float av = bkv[C_ + t];
    for (int c = 0; c < C_; c++) {
        float xv = xp[c];
        ak += xv * Wkv[c * 2 * C_ + t];
        av += xv * Wkv[c * 2 * C_ + C_ + t];
    }
    float nk = fmaxf(sqrtf(half_reduce(ak * ak)), 1e-12f);
    size_t o = (size_t)cell * C_ + t;
    kpn_u[o] = f2bf_u(ak / nk);
    vp[o]  = av;
}

// ---------------- kernel P: pooled logits (32 tokens/block) ----------------
__global__ __launch_bounds__(256) void k_plog(
    const float* __restrict__ Z, const uint32_t* __restrict__ kpnu,
    ushort* __restrict__ plogu)
{
    const int b  = blockIdx.x / (N_ / 32);
    const int t0 = (blockIdx.x % (N_ / 32)) * 32;
    const int t = threadIdx.x;
    __shared__ __align__(16) uint32_t kps[49 * SD];
    for (int idx = t; idx < 49 * 128; idx += 256) {
        int p = idx >> 7, jj = idx & 127;
        uint32_t val = kpnu[((size_t)b * P_ + p) * 128 + jj];
        int h2 = jj >> 4, j = jj & 15;
        kps[p * SD + h2 * 16 + ((j + 2 * h2) & 15)] = val;
    }
    const int tok = t >> 3, h = t & 7;
    const size_t flat = (size_t)b * N_ + t0 + tok;
    float4 qf[8];
    const float4* qrow = reinterpret_cast<const float4*>(Z + flat * ZSTR + h * HD);
#pragma unroll
    for (int j = 0; j < 8; j++) qf[j] = qrow[j];
    __syncthreads();

    size_t obase = (flat * NH + h) * PLSTR;      // ushort index, even
    uint32_t* out32 = (uint32_t*)(plogu + obase);
#pragma unroll
    for (int pp = 0; pp < 24; pp++) {
        float a0 = dot32(&kps[(2 * pp) * SD + h * 16], qf, h);
        float a1 = dot32(&kps[(2 * pp + 1) * SD + h * 16], qf, h);
        out32[pp] = (uint32_t)f2bf_u(a0) | ((uint32_t)f2bf_u(a1) << 16);
    }
    float a48 = dot32(&kps[48 * SD + h * 16], qf, h);
    plogu[obase + 48] = f2bf_u(a48);
}

// ---------------- kernel C: window logits + softmax + merged coef (4x4 tile) ----------------
__global__ __launch_bounds__(256) void k_coef(
    float* __restrict__ Z,               // qn+tokc in, coef out (ushort view)
    const uint32_t* __restrict__ knu,
    const ushort* __restrict__ plogu)
{
    const int b    = blockIdx.x / 196;
    const int tile = blockIdx.x % 196;
    const int ty = tile / 14, tx = tile % 14;
    const int t = threadIdx.x;
    __shared__ __align__(16) uint32_t ks[64 * SD];

    // stage 8x8 k rows (bf16 pairs, swizzled), OOB rows -> 0
    for (int idx = t; idx < 64 * 64; idx += 256) {
        int r = idx >> 6, u = idx & 63;
        int gy = ty * 4 + (r >> 3) - 2, gx = tx * 4 + (r & 7) - 2;
        uint32_t v0 = 0, v1 = 0;
        if (gy >= 0 && gy < H_ && gx >= 0 && gx < W_) {
            uint2 val = *reinterpret_cast<const uint2*>(
                knu + ((size_t)b * N_ + gy * W_ + gx) * 128 + 2 * u);
            v0 = val.x; v1 = val.y;
        }
        int jj = 2 * u;
        int h2 = jj >> 4, j0 = jj & 15;
        ks[r * SD + h2 * 16 + ((j0 + 2 * h2) & 15)]     = v0;
        ks[r * SD + h2 * 16 + ((j0 + 1 + 2 * h2) & 15)] = v1;
    }

    const int pair = t >> 1, half = t & 1;
    const int tok = pair >> 3, h = pair & 7;
    const int iy = tok >> 2, ix = tok & 3;
    const int gy0 = ty * 4 + iy, gx0 = tx * 4 + ix;
    const size_t flat = (size_t)b * N_ + gy0 * W_ + gx0;

    float4 qf[8];
    {
        const float4* qrow = reinterpret_cast<const float4*>(Z + flat * ZSTR + h * HD);
#pragma unroll
        for (int j = 0; j < 8; j++) qf[j] = qrow[j];
    }
    __syncthreads();

    // window slots: l = half*13 + k (valid when l < 25)
    float lgW[13], tokm[13];
    const float* tokc = Z + flat * ZSTR + 256 + h * 34;
#pragma unroll
    for (int k = 0; k < 13; k++) {
        int l = half * 13 + k;
        bool slot = (l < 25);
        int dy = l / 5 - 2, dx = l % 5 - 2;
        int gy = gy0 + dy, gx = gx0 + dx;
        bool in = slot && gy >= 0 && gy < H_ && gx >= 0 && gx < W_;
        float a = -INFINITY;
        if (in) {
            int r = (iy + dy + 2) * 8 + (ix + dx + 2);
            a = dot32(&ks[r * SD + h * 16], qf, h);
        }
        lgW[k] = a;
        float tm = 0.f;
        if (slot) {
            bool inner = (dy >= -1 && dy <= 1 && dx >= -1 && dx <= 1);
            tm = tokc[9 + l];
            if (inner) tm += tokc[(dy + 1) * 3 + (dx + 1)];
        }
        tokm[k] = tm;
    }
    // pooled slots: p = half*24 + k (valid when k < 24+half)
    float lgP[25];
    {
        const ushort* pl = plogu + (flat * NH + h) * PLSTR + half * 24;
#pragma unroll
        for (int k = 0; k < 25; k++)
            lgP[k] = (k < 24 + half) ? bfu2f(pl[k]) : -INFINITY;
    }

    // softmax partials (pair combine via shfl_xor(1))
    float m = -INFINITY;
#pragma unroll
    for (int k = 0; k < 13; k++) m = fmaxf(m, lgW[k]);
#pragma unroll
    for (int k = 0; k < 25; k++) m = fmaxf(m, lgP[k]);
    float e = 0.f;
#pragma unroll
    for (int k = 0; k < 13; k++) {
        int l = half * 13 + k;
        int dy = l / 5 - 2, dx = l % 5 - 2;
        bool inner = (l < 25) && (dy >= -1 && dy <= 1 && dx >= -1 && dx <= 1);
        e += (inner ? 2.0f : 1.0f) * __expf(lgW[k] - m);
    }
#pragma unroll
    for (int k = 0; k < 25; k++) e += __expf(lgP[k] - m);

    float mo = __shfl_xor(m, 1);
    float eo = __shfl_xor(e, 1);
    float mN = fmaxf(m, mo);
    float etot = e * __expf(m - mN) + eo * __expf(mo - mN);
    float scale = __expf(m - mN) / etot;   // multiply own exp(lg - m)

    __syncthreads();   // all Z (q, tokc) reads done before coef overwrite

    ushort* coefu = (ushort*)(Z + flat * ZSTR);  // [h][76]: 0..24 window, 25..73 pooled
#pragma unroll
    for (int k = 0; k < 13; k++) {
        int l = half * 13 + k;
        if (l < 25) {
            int dy = l / 5 - 2, dx = l % 5 - 2;
            bool inner = (dy >= -1 && dy <= 1 && dx >= -1 && dx <= 1);
            float w = (inner ? 2.0f : 1.0f) * __expf(lgW[k] - m) * scale + tokm[k];
            coefu[h * 76 + l] = f2bf_u(w);
        }
    }
#pragma unroll
    for (int k = 0; k < 25; k++) {
        if (k < 24 + half) {
            int p = half * 24 + k;
            coefu[h * 76 + 25 + p] = f2bf_u(__expf(lgP[k] - m) * scale);
        }
    }
}

// ---------------- kernel V: weighted sums (8 tokens/block) ----------------
__global__ __launch_bounds__(256) void k_av(
    const float* __restrict__ Z,          // coef (ushort view)
    const uint32_t* __restrict__ vu,      // v bf16 pairs
    const float* __restrict__ vp,
    float* __restrict__ outp)
{
    const int r0 = blockIdx.x * ROWS;     // 8 consecutive flat tokens (same image row)
    const int t = threadIdx.x;
    __shared__ ushort coefS[ROWS * 608];
    __shared__ uint32_t vpS[49 * 128];

    const int b = r0 / N_;
    {
        uint32_t* cS = (uint32_t*)coefS;
        for (int idx = t; idx < ROWS * 304; idx += 256) {
            int tk = idx / 304, d = idx % 304;
            cS[tk * 304 + d] = ((const uint32_t*)(Z + (size_t)(r0 + tk) * ZSTR))[d];
        }
    }
    for (int idx = t; idx < 49 * 128; idx += 256) {
        int p = idx >> 7, cp = idx & 127;
        const float* vr = vp + ((size_t)b * P_ + p) * C_ + 2 * cp;
        vpS[idx] = (uint32_t)f2bf_u(vr[0]) | ((uint32_t)f2bf_u(vr[1]) << 16);
    }
    __syncthreads();

    const int cpair = t & 127, tkh = t >> 7;
    const int h = cpair >> 4;
    const int n0 = r0 % N_;
    const int y = n0 / W_, x0 = n0 % W_;

    for (int tq = 0; tq < 4; tq++) {
        int tk = tkh * 4 + tq;
        int x = x0 + tk;
        float acc0 = 0.f, acc1 = 0.f;
        const ushort* cf = &coefS[tk * 608 + h * 76];
#pragma unroll
        for (int l = 0; l < 25; l++) {
            int dy = l / 5 - 2, dx = l % 5 - 2;
            int yy = y + dy, xx2 = x + dx;
            if (yy < 0 || yy >= H_ || xx2 < 0 || xx2 >= W_) continue;
            float w = bfu2f(cf[l]);
            uint32_t vv = vu[((size_t)b * N_ + yy * W_ + xx2) * 128 + cpair];
            acc0 += w * __uint_as_float(vv << 16);
            acc1 += w * __uint_as_float(vv & 0xffff0000u);
        }
#pragma unroll 7
        for (int p = 0; p < 49; p++) {
            float w = bfu2f(cf[25 + p]);
            uint32_t vv = vpS[p * 128 + cpair];
            acc0 += w * __uint_as_float(vv << 16);
            acc1 += w * __uint_as_float(vv & 0xffff0000u);
        }
        float2* o = (float2*)(outp + (size_t)(r0 + tk) * C_);
        o[cpair] = make_float2(acc0, acc1);
    }
}

// ---------------- kernel D: output projection, in-place on d_out ----------------
__global__ __launch_bounds__(256) void k_proj(
    float* __restrict__ io,
    const float* __restrict__ Wproj, const float* __restrict__ bproj)
{
    const int r0 = blockIdx.x * ROWS;
    const int t = threadIdx.x;
    __shared__ float ps[ROWS][C_ + 1];
#pragma unroll
    for (int r = 0; r < ROWS; r++) ps[r][t] = io[(size_t)(r0 + r) * C_ + t];
    __syncthreads();

    float o[ROWS];
    const float bp = bproj[t];
#pragma unroll
    for (int r = 0; r < ROWS; r++) o[r] = bp;
    for (int c = 0; c < C_; c++) {
        float w = Wproj[c * C_ + t];
#pragma unroll
        for (int r = 0; r < ROWS; r++) o[r] += ps[r][c] * w;
    }
#pragma unroll
    for (int r = 0; r < ROWS; r++) io[(size_t)(r0 + r) * C_ + t] = o[r];
}

extern "C" void kernel_launch(void* const* d_in, const int* in_sizes, int n_in,
                              void* d_out, int out_size, void* d_ws, size_t ws_size,
                              hipStream_t stream)
{
    (void)in_sizes; (void)n_in; (void)out_size; (void)ws_size;
    const float* x     = (const float*)d_in[0];
    const float* Wq    = (const float*)d_in[1];
    const float* bq    = (const float*)d_in[2];
    const float* Wkv   = (const float*)d_in[3];
    const float* bkv   = (const float*)d_in[4];
    const float* Wsr   = (const float*)d_in[5];
    const float* bsr   = (const float*)d_in[6];
    const float* ln_g  = (const float*)d_in[7];
    const float* ln_b  = (const float*)d_in[8];
    const float* tok1  = (const float*)d_in[9];
    const float* bias1 = (const float*)d_in[10];
    const float* tok2  = (const float*)d_in[11];
    const float* bias2 = (const float*)d_in[12];
    const float* Wproj = (const float*)d_in[13];
    const float* bproj = (const float*)d_in[14];
    float* out = (float*)d_out;

    const size_t nz    = (size_t)B_ * N_ * ZSTR;    // Z records
    const size_t nvu   = (size_t)B_ * N_ * 128;     // v bf16 pairs (dwords)
    const size_t nknu  = (size_t)B_ * N_ * 128;     // kn bf16 pairs (dwords)
    const size_t nvp   = (size_t)B_ * P_ * C_;
    const size_t nkpnu = (size_t)B_ * P_ * 128;

    float*    Zb     = (float*)d_ws;
    uint32_t* vu     = (uint32_t*)(Zb + nz);
    uint32_t* knu    = vu + nvu;
    float*    vp     = (float*)(knu + nknu);
    uint32_t* kpnu   = (uint32_t*)(vp + nvp);
    float*    srpart = (float*)(kpnu + nkpnu);

    ushort* plogu = (ushort*)d_out;   // pooled logits live in d_out until k_av overwrites

    k_qkv<<<B_ * N_ / ROWS, 256, 0, stream>>>(x, Wq, bq, Wkv, bkv,
                                              tok1, bias1, tok2, bias2,
                                              Zb, (ushort*)knu, (ushort*)vu);
    k_sr1<<<B_ * P_ * 8, 256, 0, stream>>>(x, Wsr, bsr, srpart);
    k_sr2<<<B_ * P_, 256, 0, stream>>>(srpart, Wkv, bkv, ln_g, ln_b,
                                       (ushort*)kpnu, vp);
    k_plog<<<B_ * (N_ / 32), 256, 0, stream>>>(Zb, kpnu, plogu);
    k_coef<<<B_ * 196, 256, 0, stream>>>(Zb, knu, plogu);
    k_av<<<B_ * N_ / ROWS, 256, 0, stream>>>(Zb, vu, vp, out);
    k_proj<<<B_ * N_ / ROWS, 256, 0, stream>>>(out, Wproj, bproj);
}

// Round 6
// 216.311 us; speedup vs baseline: 4.0102x; 1.5885x over previous
//
#include <hip/hip_runtime.h>
#include <hip/hip_bf16.h>

using bf16 = __hip_bfloat16;

#define B_  4
#define H_  56
#define W_  56
#define N_  3136
#define C_  256
#define NH  8
#define HD  32
#define P_  49
#define PH  7
#define ROWS 8
#define SD  132          // LDS row stride (dwords) for swizzled bf16-pair rows
#define TOKC 272         // 8 heads * 34 token coefficients
#define ZSTR 392         // Z record stride (dwords): 256 qn f32 + 136 dw (272 bf16 tokc)
#define PLSTR 52         // plog stride (ushorts) per (token,head)

typedef __attribute__((ext_vector_type(8))) short short8;
typedef __attribute__((ext_vector_type(4))) float f32x4;

__device__ __forceinline__ float bfu2f(ushort u) { return __uint_as_float((uint32_t)u << 16); }
__device__ __forceinline__ ushort f2bf_u(float f) {
    uint32_t u = __float_as_uint(f);
    uint32_t r = (u + 0x7FFFu + ((u >> 16) & 1u)) >> 16;
    return (ushort)r;
}

__device__ __forceinline__ float half_reduce(float v) {
#pragma unroll
    for (int m = 16; m >= 1; m >>= 1) v += __shfl_xor(v, m);
    return v;
}

__device__ __forceinline__ float block_sum(float val, float* red) {
#pragma unroll
    for (int m = 32; m >= 1; m >>= 1) val += __shfl_xor(val, m);
    __syncthreads();
    if ((threadIdx.x & 63) == 0) red[threadIdx.x >> 6] = val;
    __syncthreads();
    return red[0] + red[1] + red[2] + red[3];
}

// dot of q (8x float4) with a swizzled bf16-pair LDS row segment for head h2
__device__ __forceinline__ float dot32(const uint32_t* row, const float4* qf, int h2) {
    float a = 0.f;
#pragma unroll
    for (int jp = 0; jp < 8; jp++) {
        int pc = (2 * jp + 2 * h2) & 15;
        uint2 w = *reinterpret_cast<const uint2*>(row + pc);
        float4 q = qf[jp];
        a += q.x * __uint_as_float(w.x << 16);
        a += q.y * __uint_as_float(w.x & 0xffff0000u);
        a += q.z * __uint_as_float(w.y << 16);
        a += q.w * __uint_as_float(w.y & 0xffff0000u);
    }
    return a;
}

// ---------------- prep: bf16 conversions + weight transposes ----------------
__global__ __launch_bounds__(256) void k_prep(
    const float* __restrict__ x,
    const float* __restrict__ Wq, const float* __restrict__ Wkv,
    const float* __restrict__ Wsr, const float* __restrict__ Wproj,
    ushort* __restrict__ xbf, ushort* __restrict__ WT, ushort* __restrict__ WTp)
{
    const int gid = blockIdx.x * 256 + threadIdx.x;
    const int gs = gridDim.x * 256;
    for (int i = gid; i < B_ * N_ * C_; i += gs) xbf[i] = f2bf_u(x[i]);
    for (int i = gid; i < 1024 * 256; i += gs) {
        int o = i >> 8, c = i & 255;
        float w = (o < 256) ? Wq[c * 256 + o]
                : (o < 768) ? Wkv[c * 512 + (o - 256)]
                            : Wsr[c * 256 + (o - 768)];
        WT[i] = f2bf_u(w);
    }
    for (int i = gid; i < 256 * 256; i += gs) {
        int o = i >> 8, c = i & 255;
        WTp[i] = f2bf_u(Wproj[c * 256 + o]);
    }
}

// ---------------- MFMA GEMM 64x64 tile, K=256. MODE: 0=q(norm,f32->Z) 1=k(norm,bf16)
// 2=v(bf16) 3=sr(gelu,bf16) 4=proj(f32->out) ----------------
template <int MODE>
__global__ __launch_bounds__(256) void k_gemm(
    const ushort* __restrict__ Abf,   // [Mtot][256] bf16
    const ushort* __restrict__ WT,    // [256 cols of this mode][256] bf16 (pre-offset)
    const float*  __restrict__ bias,  // [256] (pre-offset)
    float* __restrict__ dstF,
    ushort* __restrict__ dstU)
{
    const int r0 = blockIdx.x * 64;
    const int cb = blockIdx.y * 64;
    const int t = threadIdx.x;
    __shared__ __align__(16) ushort As[64 * 264];
    __shared__ __align__(16) ushort Bs[64 * 264];

#pragma unroll
    for (int i = 0; i < 8; i++) {
        int chunk = t + i * 256;
        int row = chunk >> 5, ks = (chunk & 31) * 8;
        *(uint4*)(As + row * 264 + ks) = *(const uint4*)(Abf + (size_t)(r0 + row) * 256 + ks);
        *(uint4*)(Bs + row * 264 + ks) = *(const uint4*)(WT + (size_t)(cb + row) * 256 + ks);
    }
    __syncthreads();

    const int w = t >> 6, lane = t & 63;
    const int arow = w * 16 + (lane & 15);
    const int k0 = (lane >> 4) * 8;
    f32x4 acc[4];
#pragma unroll
    for (int ct = 0; ct < 4; ct++) acc[ct] = (f32x4){0.f, 0.f, 0.f, 0.f};

#pragma unroll
    for (int kk = 0; kk < 8; kk++) {
        short8 a = *(const short8*)(As + arow * 264 + kk * 32 + k0);
#pragma unroll
        for (int ct = 0; ct < 4; ct++) {
            short8 b = *(const short8*)(Bs + (ct * 16 + (lane & 15)) * 264 + kk * 32 + k0);
            acc[ct] = __builtin_amdgcn_mfma_f32_16x16x32_bf16(a, b, acc[ct], 0, 0, 0);
        }
    }

    const int colq = lane & 15;
    const int rb = r0 + w * 16 + (lane >> 4) * 4;
#pragma unroll
    for (int ct = 0; ct < 4; ct++) {
        float bv = bias[cb + ct * 16 + colq];
#pragma unroll
        for (int j = 0; j < 4; j++) acc[ct][j] += bv;
    }

    if (MODE == 0 || MODE == 1) {
        // per-row L2 normalize over each head (32 cols = 2 ctiles)
#pragma unroll
        for (int hp = 0; hp < 2; hp++) {
#pragma unroll
            for (int j = 0; j < 4; j++) {
                float ss = acc[2 * hp][j] * acc[2 * hp][j] + acc[2 * hp + 1][j] * acc[2 * hp + 1][j];
                ss += __shfl_xor(ss, 1); ss += __shfl_xor(ss, 2);
                ss += __shfl_xor(ss, 4); ss += __shfl_xor(ss, 8);
                float inv = 1.0f / fmaxf(sqrtf(ss), 1e-12f);
                acc[2 * hp][j] *= inv; acc[2 * hp + 1][j] *= inv;
            }
        }
    }
    if (MODE == 3) {
#pragma unroll
        for (int ct = 0; ct < 4; ct++)
#pragma unroll
            for (int j = 0; j < 4; j++) {
                float s = acc[ct][j];
                acc[ct][j] = 0.5f * s * (1.0f + erff(s * 0.70710678118654752f));
            }
    }

#pragma unroll
    for (int ct = 0; ct < 4; ct++) {
        int gcol = cb + ct * 16 + colq;
#pragma unroll
        for (int j = 0; j < 4; j++) {
            if (MODE == 0)      dstF[(size_t)(rb + j) * ZSTR + gcol] = acc[ct][j];
            else if (MODE == 4) dstF[(size_t)(rb + j) * 256 + gcol] = acc[ct][j];
            else                dstU[(size_t)(rb + j) * 256 + gcol] = f2bf_u(acc[ct][j]);
        }
    }
}

// ---------------- pool: mean over 8x8 pixels of gelu(sr) ----------------
__global__ __launch_bounds__(256) void k_pool(
    const ushort* __restrict__ srg, float* __restrict__ srpool)
{
    const int cell = blockIdx.x;   // b*P + p
    const int b = cell / P_, p = cell % P_;
    const int py = p / PH, px = p % PH;
    const int t = threadIdx.x;
    float acc = 0.f;
    for (int pi = 0; pi < 64; pi++) {
        int n = (py * 8 + (pi >> 3)) * W_ + px * 8 + (pi & 7);
        acc += bfu2f(srg[((size_t)b * N_ + n) * 256 + t]);
    }
    srpool[(size_t)cell * 256 + t] = acc * (1.0f / 64.0f);
}

// ---------------- sr2: LN + kv proj + normalize ----------------
__global__ __launch_bounds__(256) void k_sr2(
    const float* __restrict__ srpool,
    const float* __restrict__ Wkv, const float* __restrict__ bkv,
    const float* __restrict__ ln_g, const float* __restrict__ ln_b,
    ushort* __restrict__ kpn_u, float* __restrict__ vp)
{
    const int cell = blockIdx.x;
    const int t = threadIdx.x;
    __shared__ float xp[C_];
    __shared__ float red[4];

    float acc = srpool[(size_t)cell * C_ + t];
    float mean = block_sum(acc, red) * (1.0f / C_);
    float dv = acc - mean;
    float var = block_sum(dv * dv, red) * (1.0f / C_);
    float xpv = dv * rsqrtf(var + 1e-5f) * ln_g[t] + ln_b[t];
    xp[t] = xpv;
    __syncthreads();

    float ak = bkv[t];
    float av = bkv[C_ + t];
    for (int c = 0; c < C_; c++) {
        float xv = xp[c];
        ak += xv * Wkv[c * 2 * C_ + t];
        av += xv * Wkv[c * 2 * C_ + C_ + t];
    }
    float nk = fmaxf(sqrtf(half_reduce(ak * ak)), 1e-12f);
    size_t o = (size_t)cell * C_ + t;
    kpn_u[o] = f2bf_u(ak / nk);
    vp[o]  = av;
}

// ---------------- tokc: q . tok + bias -> bf16 into Z tail ----------------
__global__ __launch_bounds__(256) void k_tokc(
    float* __restrict__ Z,
    const float* __restrict__ tok1, const float* __restrict__ bias1,
    const float* __restrict__ tok2, const float* __restrict__ bias2)
{
    const int r0 = blockIdx.x * ROWS;
    const int t = threadIdx.x;
    __shared__ float xs[ROWS][C_ + 1];
    __shared__ float tokL[TOKC * 33];

    for (int idx = t; idx < TOKC * 32; idx += 256) {
        int hl = idx >> 5, d = idx & 31;
        int h = hl / 34, l = hl % 34;
        float val = (l < 9) ? tok1[(h * HD + d) * 9 + l]
                            : tok2[(h * HD + d) * 25 + (l - 9)];
        tokL[hl * 33 + d] = val;
    }
#pragma unroll
    for (int r = 0; r < ROWS; r++) xs[r][t] = Z[(size_t)(r0 + r) * ZSTR + t];
    __syncthreads();

    for (int out = t; out < ROWS * TOKC; out += 256) {
        int r = out / TOKC, c = out % TOKC;
        int h = c / 34, l = c % 34;
        float s = (l < 9) ? bias1[h * 9 + l] : bias2[h * 25 + (l - 9)];
        const float* tl = &tokL[c * 33];
        const float* qrow = &xs[r][h * HD];
#pragma unroll
        for (int d = 0; d < 32; d++) s += qrow[d] * tl[d];
        ((ushort*)(Z + (size_t)(r0 + r) * ZSTR + 256))[c] = f2bf_u(s);
    }
}

// ---------------- plog: pooled logits (32 tokens/block) ----------------
__global__ __launch_bounds__(256) void k_plog(
    const float* __restrict__ Z, const uint32_t* __restrict__ kpnu,
    ushort* __restrict__ plogu)
{
    const int b  = blockIdx.x / (N_ / 32);
    const int t0 = (blockIdx.x % (N_ / 32)) * 32;
    const int t = threadIdx.x;
    __shared__ __align__(16) uint32_t kps[49 * SD];
    for (int idx = t; idx < 49 * 128; idx += 256) {
        int p = idx >> 7, jj = idx & 127;
        uint32_t val = kpnu[((size_t)b * P_ + p) * 128 + jj];
        int h2 = jj >> 4, j = jj & 15;
        kps[p * SD + h2 * 16 + ((j + 2 * h2) & 15)] = val;
    }
    const int tok = t >> 3, h = t & 7;
    const size_t flat = (size_t)b * N_ + t0 + tok;
    float4 qf[8];
    const float4* qrow = reinterpret_cast<const float4*>(Z + flat * ZSTR + h * HD);
#pragma unroll
    for (int j = 0; j < 8; j++) qf[j] = qrow[j];
    __syncthreads();

    size_t obase = (flat * NH + h) * PLSTR;
    uint32_t* out32 = (uint32_t*)(plogu + obase);
#pragma unroll
    for (int pp = 0; pp < 24; pp++) {
        float a0 = dot32(&kps[(2 * pp) * SD + h * 16], qf, h);
        float a1 = dot32(&kps[(2 * pp + 1) * SD + h * 16], qf, h);
        out32[pp] = (uint32_t)f2bf_u(a0) | ((uint32_t)f2bf_u(a1) << 16);
    }
    float a48 = dot32(&kps[48 * SD + h * 16], qf, h);
    plogu[obase + 48] = f2bf_u(a48);
}

// ---------------- coef: window logits + softmax + merged coef (4x4 tile) ----------------
__global__ __launch_bounds__(256) void k_coef(
    float* __restrict__ Z,
    const uint32_t* __restrict__ knu,
    const ushort* __restrict__ plogu)
{
    const int b    = blockIdx.x / 196;
    const int tile = blockIdx.x % 196;
    const int ty = tile / 14, tx = tile % 14;
    const int t = threadIdx.x;
    __shared__ __align__(16) uint32_t ks[64 * SD];

    for (int idx = t; idx < 64 * 64; idx += 256) {
        int r = idx >> 6, u = idx & 63;
        int gy = ty * 4 + (r >> 3) - 2, gx = tx * 4 + (r & 7) - 2;
        uint32_t v0 = 0, v1 = 0;
        if (gy >= 0 && gy < H_ && gx >= 0 && gx < W_) {
            uint2 val = *reinterpret_cast<const uint2*>(
                knu + ((size_t)b * N_ + gy * W_ + gx) * 128 + 2 * u);
            v0 = val.x; v1 = val.y;
        }
        int jj = 2 * u;
        int h2 = jj >> 4, j0 = jj & 15;
        ks[r * SD + h2 * 16 + ((j0 + 2 * h2) & 15)]     = v0;
        ks[r * SD + h2 * 16 + ((j0 + 1 + 2 * h2) & 15)] = v1;
    }

    const int pair = t >> 1, half = t & 1;
    const int tok = pair >> 3, h = pair & 7;
    const int iy = tok >> 2, ix = tok & 3;
    const int gy0 = ty * 4 + iy, gx0 = tx * 4 + ix;
    const size_t flat = (size_t)b * N_ + gy0 * W_ + gx0;

    float4 qf[8];
    {
        const float4* qrow = reinterpret_cast<const float4*>(Z + flat * ZSTR + h * HD);
#pragma unroll
        for (int j = 0; j < 8; j++) qf[j] = qrow[j];
    }
    __syncthreads();

    float lgW[13], tokm[13];
    const ushort* tokcu = (const ushort*)(Z + flat * ZSTR + 256) + h * 34;
#pragma unroll
    for (int k = 0; k < 13; k++) {
        int l = half * 13 + k;
        bool slot = (l < 25);
        int dy = l / 5 - 2, dx = l % 5 - 2;
        int gy = gy0 + dy, gx = gx0 + dx;
        bool in = slot && gy >= 0 && gy < H_ && gx >= 0 && gx < W_;
        float a = -INFINITY;
        if (in) {
            int r = (iy + dy + 2) * 8 + (ix + dx + 2);
            a = dot32(&ks[r * SD + h * 16], qf, h);
        }
        lgW[k] = a;
        float tm = 0.f;
        if (slot) {
            bool inner = (dy >= -1 && dy <= 1 && dx >= -1 && dx <= 1);
            tm = bfu2f(tokcu[9 + l]);
            if (inner) tm += bfu2f(tokcu[(dy + 1) * 3 + (dx + 1)]);
        }
        tokm[k] = tm;
    }
    float lgP[25];
    {
        const ushort* pl = plogu + (flat * NH + h) * PLSTR + half * 24;
#pragma unroll
        for (int k = 0; k < 25; k++)
            lgP[k] = (k < 24 + half) ? bfu2f(pl[k]) : -INFINITY;
    }

    float m = -INFINITY;
#pragma unroll
    for (int k = 0; k < 13; k++) m = fmaxf(m, lgW[k]);
#pragma unroll
    for (int k = 0; k < 25; k++) m = fmaxf(m, lgP[k]);
    float e = 0.f;
#pragma unroll
    for (int k = 0; k < 13; k++) {
        int l = half * 13 + k;
        int dy = l / 5 - 2, dx = l % 5 - 2;
        bool inner = (l < 25) && (dy >= -1 && dy <= 1 && dx >= -1 && dx <= 1);
        e += (inner ? 2.0f : 1.0f) * __expf(lgW[k] - m);
    }
#pragma unroll
    for (int k = 0; k < 25; k++) e += __expf(lgP[k] - m);

    float mo = __shfl_xor(m, 1);
    float eo = __shfl_xor(e, 1);
    float mN = fmaxf(m, mo);
    float etot = e * __expf(m - mN) + eo * __expf(mo - mN);
    float scale = __expf(m - mN) / etot;

    __syncthreads();   // all Z (q, tokc) reads done before coef overwrite

    ushort* coefu = (ushort*)(Z + flat * ZSTR);  // [h][76]: 0..24 window, 25..73 pooled
#pragma unroll
    for (int k = 0; k < 13; k++) {
        int l = half * 13 + k;
        if (l < 25) {
            int dy = l / 5 - 2, dx = l % 5 - 2;
            bool inner = (dy >= -1 && dy <= 1 && dx >= -1 && dx <= 1);
            float w = (inner ? 2.0f : 1.0f) * __expf(lgW[k] - m) * scale + tokm[k];
            coefu[h * 76 + l] = f2bf_u(w);
        }
    }
#pragma unroll
    for (int k = 0; k < 25; k++) {
        if (k < 24 + half) {
            int p = half * 24 + k;
            coefu[h * 76 + 25 + p] = f2bf_u(__expf(lgP[k] - m) * scale);
        }
    }
}

// ---------------- av: weighted sums (8 tokens/block) -> bf16 pre ----------------
__global__ __launch_bounds__(256) void k_av(
    const float* __restrict__ Z,
    const uint32_t* __restrict__ vu,
    const float* __restrict__ vp,
    uint32_t* __restrict__ pre_bfu)
{
    const int r0 = blockIdx.x * ROWS;
    const int t = threadIdx.x;
    __shared__ ushort coefS[ROWS * 608];
    __shared__ uint32_t vpS[49 * 128];

    const int b = r0 / N_;
    {
        uint32_t* cS = (uint32_t*)coefS;
        for (int idx = t; idx < ROWS * 304; idx += 256) {
            int tk = idx / 304, d = idx % 304;
            cS[tk * 304 + d] = ((const uint32_t*)(Z + (size_t)(r0 + tk) * ZSTR))[d];
        }
    }
    for (int idx = t; idx < 49 * 128; idx += 256) {
        int p = idx >> 7, cp = idx & 127;
        const float* vr = vp + ((size_t)b * P_ + p) * C_ + 2 * cp;
        vpS[idx] = (uint32_t)f2bf_u(vr[0]) | ((uint32_t)f2bf_u(vr[1]) << 16);
    }
    __syncthreads();

    const int cpair = t & 127, tkh = t >> 7;
    const int h = cpair >> 4;
    const int n0 = r0 % N_;
    const int y = n0 / W_, x0 = n0 % W_;

    for (int tq = 0; tq < 4; tq++) {
        int tk = tkh * 4 + tq;
        int x = x0 + tk;
        float acc0 = 0.f, acc1 = 0.f;
        const ushort* cf = &coefS[tk * 608 + h * 76];
#pragma unroll
        for (int l = 0; l < 25; l++) {
            int dy = l / 5 - 2, dx = l % 5 - 2;
            int yy = y + dy, xx2 = x + dx;
            if (yy < 0 || yy >= H_ || xx2 < 0 || xx2 >= W_) continue;
            float w = bfu2f(cf[l]);
            uint32_t vv = vu[((size_t)b * N_ + yy * W_ + xx2) * 128 + cpair];
            acc0 += w * __uint_as_float(vv << 16);
            acc1 += w * __uint_as_float(vv & 0xffff0000u);
        }
#pragma unroll 7
        for (int p = 0; p < 49; p++) {
            float w = bfu2f(cf[25 + p]);
            uint32_t vv = vpS[p * 128 + cpair];
            acc0 += w * __uint_as_float(vv << 16);
            acc1 += w * __uint_as_float(vv & 0xffff0000u);
        }
        pre_bfu[(size_t)(r0 + tk) * 128 + cpair] =
            (uint32_t)f2bf_u(acc0) | ((uint32_t)f2bf_u(acc1) << 16);
    }
}

extern "C" void kernel_launch(void* const* d_in, const int* in_sizes, int n_in,
                              void* d_out, int out_size, void* d_ws, size_t ws_size,
                              hipStream_t stream)
{
    (void)in_sizes; (void)n_in; (void)out_size; (void)ws_size;
    const float* x     = (const float*)d_in[0];
    const float* Wq    = (const float*)d_in[1];
    const float* bq    = (const float*)d_in[2];
    const float* Wkv   = (const float*)d_in[3];
    const float* bkv   = (const float*)d_in[4];
    const float* Wsr   = (const float*)d_in[5];
    const float* bsr   = (const float*)d_in[6];
    const float* ln_g  = (const float*)d_in[7];
    const float* ln_b  = (const float*)d_in[8];
    const float* tok1  = (const float*)d_in[9];
    const float* bias1 = (const float*)d_in[10];
    const float* tok2  = (const float*)d_in[11];
    const float* bias2 = (const float*)d_in[12];
    const float* Wproj = (const float*)d_in[13];
    const float* bproj = (const float*)d_in[14];
    float* out = (float*)d_out;

    const size_t nz   = (size_t)B_ * N_ * ZSTR;    // 4,917,248 dw
    const size_t nhalf = (size_t)B_ * N_ * 128;    // 1,605,632 dw per bf16 plane

    float*    Zb     = (float*)d_ws;
    uint32_t* xbf    = (uint32_t*)(Zb + nz);       // aliased: pre_bf after GEMMs
    uint32_t* vu     = xbf + nhalf;
    uint32_t* knu    = vu + nhalf;
    uint32_t* srgu   = knu + nhalf;
    ushort*   WTus   = (ushort*)(srgu + nhalf);    // 1024*256 bf16
    ushort*   WTpus  = WTus + 1024 * 256;          // 256*256 bf16
    float*    vp     = (float*)(WTpus + 256 * 256);
    uint32_t* kpnu   = (uint32_t*)(vp + (size_t)B_ * P_ * C_);
    float*    srpool = (float*)(kpnu + (size_t)B_ * P_ * 128);

    ushort* plogu = (ushort*)d_out;   // pooled logits live in d_out until final GEMM

    dim3 g64(196, 4);

    k_prep<<<2048, 256, 0, stream>>>(x, Wq, Wkv, Wsr, Wproj,
                                     (ushort*)xbf, WTus, WTpus);
    k_gemm<0><<<g64, 256, 0, stream>>>((ushort*)xbf, WTus,             bq,        Zb, nullptr);
    k_gemm<1><<<g64, 256, 0, stream>>>((ushort*)xbf, WTus + 256 * 256, bkv,       nullptr, (ushort*)knu);
    k_gemm<2><<<g64, 256, 0, stream>>>((ushort*)xbf, WTus + 512 * 256, bkv + 256, nullptr, (ushort*)vu);
    k_gemm<3><<<g64, 256, 0, stream>>>((ushort*)xbf, WTus + 768 * 256, bsr,       nullptr, (ushort*)srgu);
    k_pool<<<B_ * P_, 256, 0, stream>>>((const ushort*)srgu, srpool);
    k_sr2<<<B_ * P_, 256, 0, stream>>>(srpool, Wkv, bkv, ln_g, ln_b, (ushort*)kpnu, vp);
    k_tokc<<<B_ * N_ / ROWS, 256, 0, stream>>>(Zb, tok1, bias1, tok2, bias2);
    k_plog<<<B_ * (N_ / 32), 256, 0, stream>>>(Zb, kpnu, plogu);
    k_coef<<<B_ * 196, 256, 0, stream>>>(Zb, knu, plogu);
    k_av<<<B_ * N_ / ROWS, 256, 0, stream>>>(Zb, vu, vp, xbf);  // pre overwrites xbf
    k_gemm<4><<<g64, 256, 0, stream>>>((ushort*)xbf, WTpus, bproj, out, nullptr);
}

// Round 7
// 160.897 us; speedup vs baseline: 5.3913x; 1.3444x over previous
//
#include <hip/hip_runtime.h>
#include <hip/hip_bf16.h>

using bf16 = __hip_bfloat16;

#define B_  4
#define H_  56
#define W_  56
#define N_  3136
#define C_  256
#define NH  8
#define HD  32
#define P_  49
#define PH  7
#define ROWS 8
#define SD  132          // LDS row stride (dwords) for swizzled bf16-pair rows
#define TOKC 272         // 8 heads * 34 token coefficients
#define ZSTR 392         // Z record stride (dwords): 256 qn f32 + 136 dw (272 bf16 tokc)
#define PLSTR 52         // plog stride (ushorts) per (token,head)

typedef __attribute__((ext_vector_type(8))) short short8;
typedef __attribute__((ext_vector_type(4))) float f32x4;

__device__ __forceinline__ float bfu2f(ushort u) { return __uint_as_float((uint32_t)u << 16); }
__device__ __forceinline__ ushort f2bf_u(float f) {
    uint32_t u = __float_as_uint(f);
    uint32_t r = (u + 0x7FFFu + ((u >> 16) & 1u)) >> 16;
    return (ushort)r;
}
__device__ __forceinline__ float lo16(uint32_t u) { return __uint_as_float(u << 16); }
__device__ __forceinline__ float hi16(uint32_t u) { return __uint_as_float(u & 0xffff0000u); }

__device__ __forceinline__ float half_reduce(float v) {
#pragma unroll
    for (int m = 16; m >= 1; m >>= 1) v += __shfl_xor(v, m);
    return v;
}

__device__ __forceinline__ float block_sum(float val, float* red) {
#pragma unroll
    for (int m = 32; m >= 1; m >>= 1) val += __shfl_xor(val, m);
    __syncthreads();
    if ((threadIdx.x & 63) == 0) red[threadIdx.x >> 6] = val;
    __syncthreads();
    return red[0] + red[1] + red[2] + red[3];
}

// dot of q (8x float4) with a swizzled bf16-pair LDS row segment for head h2
__device__ __forceinline__ float dot32(const uint32_t* row, const float4* qf, int h2) {
    float a = 0.f;
#pragma unroll
    for (int jp = 0; jp < 8; jp++) {
        int pc = (2 * jp + 2 * h2) & 15;
        uint2 w = *reinterpret_cast<const uint2*>(row + pc);
        float4 q = qf[jp];
        a += q.x * lo16(w.x);
        a += q.y * hi16(w.x);
        a += q.z * lo16(w.y);
        a += q.w * hi16(w.y);
    }
    return a;
}

// ---------------- prep: bf16 conversions + weight transposes + tok block-diag ----------------
__global__ __launch_bounds__(256) void k_prep(
    const float* __restrict__ x,
    const float* __restrict__ Wq, const float* __restrict__ Wkv,
    const float* __restrict__ Wsr, const float* __restrict__ Wproj,
    const float* __restrict__ tok1, const float* __restrict__ bias1,
    const float* __restrict__ tok2, const float* __restrict__ bias2,
    ushort* __restrict__ xbf, ushort* __restrict__ WT, ushort* __restrict__ WTp,
    ushort* __restrict__ TD, float* __restrict__ biasT)
{
    const int gid = blockIdx.x * 256 + threadIdx.x;
    const int gs = gridDim.x * 256;
    for (int i = gid; i < B_ * N_ * C_; i += gs) xbf[i] = f2bf_u(x[i]);
    for (int i = gid; i < 1024 * 256; i += gs) {
        int o = i >> 8, c = i & 255;
        float w = (o < 256) ? Wq[c * 256 + o]
                : (o < 768) ? Wkv[c * 512 + (o - 256)]
                            : Wsr[c * 256 + (o - 768)];
        WT[i] = f2bf_u(w);
    }
    for (int i = gid; i < 256 * 256; i += gs) {
        int o = i >> 8, c = i & 255;
        WTp[i] = f2bf_u(Wproj[c * 256 + o]);
    }
    // block-diagonal tok matrix [320 cols][256 k]
    for (int i = gid; i < 320 * 256; i += gs) {
        int j = i >> 8, k = i & 255;
        float val = 0.f;
        if (j < TOKC) {
            int h = j / 34, l = j % 34;
            if ((k >> 5) == h) {
                int d = k & 31;
                val = (l < 9) ? tok1[(h * HD + d) * 9 + l]
                              : tok2[(h * HD + d) * 25 + (l - 9)];
            }
        }
        TD[i] = f2bf_u(val);
    }
    for (int i = gid; i < 320; i += gs) {
        float bv = 0.f;
        if (i < TOKC) {
            int h = i / 34, l = i % 34;
            bv = (l < 9) ? bias1[h * 9 + l] : bias2[h * 25 + (l - 9)];
        }
        biasT[i] = bv;
    }
}

// ---------------- MFMA GEMM 64x64 tile, K=256.
// MODE: 0=q(norm -> Z f32 + qn bf16) 1=k(norm,bf16) 2=v(bf16) 3=sr(gelu,bf16)
//       4=proj(f32->out) 5=tokc(bf16 -> Z tail, guard col<272) ----------------
template <int MODE>
__global__ __launch_bounds__(256) void k_gemm(
    const ushort* __restrict__ Abf,   // [Mtot][256] bf16
    const ushort* __restrict__ WT,    // [cols of this mode][256] bf16 (pre-offset)
    const float*  __restrict__ bias,  // (pre-offset)
    float* __restrict__ dstF,
    ushort* __restrict__ dstU)
{
    const int r0 = blockIdx.x * 64;
    const int cb = blockIdx.y * 64;
    const int t = threadIdx.x;
    __shared__ __align__(16) ushort As[64 * 264];
    __shared__ __align__(16) ushort Bs[64 * 264];

#pragma unroll
    for (int i = 0; i < 8; i++) {
        int chunk = t + i * 256;
        int row = chunk >> 5, ks = (chunk & 31) * 8;
        *(uint4*)(As + row * 264 + ks) = *(const uint4*)(Abf + (size_t)(r0 + row) * 256 + ks);
        *(uint4*)(Bs + row * 264 + ks) = *(const uint4*)(WT + (size_t)(cb + row) * 256 + ks);
    }
    __syncthreads();

    const int w = t >> 6, lane = t & 63;
    const int arow = w * 16 + (lane & 15);
    const int k0 = (lane >> 4) * 8;
    f32x4 acc[4];
#pragma unroll
    for (int ct = 0; ct < 4; ct++) acc[ct] = (f32x4){0.f, 0.f, 0.f, 0.f};

#pragma unroll
    for (int kk = 0; kk < 8; kk++) {
        short8 a = *(const short8*)(As + arow * 264 + kk * 32 + k0);
#pragma unroll
        for (int ct = 0; ct < 4; ct++) {
            short8 b = *(const short8*)(Bs + (ct * 16 + (lane & 15)) * 264 + kk * 32 + k0);
            acc[ct] = __builtin_amdgcn_mfma_f32_16x16x32_bf16(a, b, acc[ct], 0, 0, 0);
        }
    }

    const int colq = lane & 15;
    const int rb = r0 + w * 16 + (lane >> 4) * 4;
#pragma unroll
    for (int ct = 0; ct < 4; ct++) {
        float bv = bias[cb + ct * 16 + colq];
#pragma unroll
        for (int j = 0; j < 4; j++) acc[ct][j] += bv;
    }

    if (MODE == 0 || MODE == 1) {
        // per-row L2 normalize over each head (32 cols = 2 ctiles)
#pragma unroll
        for (int hp = 0; hp < 2; hp++) {
#pragma unroll
            for (int j = 0; j < 4; j++) {
                float ss = acc[2 * hp][j] * acc[2 * hp][j] + acc[2 * hp + 1][j] * acc[2 * hp + 1][j];
                ss += __shfl_xor(ss, 1); ss += __shfl_xor(ss, 2);
                ss += __shfl_xor(ss, 4); ss += __shfl_xor(ss, 8);
                float inv = 1.0f / fmaxf(sqrtf(ss), 1e-12f);
                acc[2 * hp][j] *= inv; acc[2 * hp + 1][j] *= inv;
            }
        }
    }
    if (MODE == 3) {
#pragma unroll
        for (int ct = 0; ct < 4; ct++)
#pragma unroll
            for (int j = 0; j < 4; j++) {
                float s = acc[ct][j];
                acc[ct][j] = 0.5f * s * (1.0f + erff(s * 0.70710678118654752f));
            }
    }

#pragma unroll
    for (int ct = 0; ct < 4; ct++) {
        int gcol = cb + ct * 16 + colq;
#pragma unroll
        for (int j = 0; j < 4; j++) {
            if (MODE == 0) {
                dstF[(size_t)(rb + j) * ZSTR + gcol] = acc[ct][j];
                dstU[(size_t)(rb + j) * 256 + gcol] = f2bf_u(acc[ct][j]);
            } else if (MODE == 4) {
                dstF[(size_t)(rb + j) * 256 + gcol] = acc[ct][j];
            } else if (MODE == 5) {
                if (gcol < TOKC)
                    ((ushort*)(dstF + (size_t)(rb + j) * ZSTR + 256))[gcol] = f2bf_u(acc[ct][j]);
            } else {
                dstU[(size_t)(rb + j) * 256 + gcol] = f2bf_u(acc[ct][j]);
            }
        }
    }
}

// ---------------- pool: mean over 8x8 pixels of gelu(sr), dword loads ----------------
__global__ __launch_bounds__(256) void k_pool(
    const uint32_t* __restrict__ srgu32, float* __restrict__ srpool)
{
    const int cell = blockIdx.x;   // b*P + p
    const int b = cell / P_, p = cell % P_;
    const int py = p / PH, px = p % PH;
    const int t = threadIdx.x;
    const int ph = t >> 7, cp = t & 127;
    __shared__ float2 part[128];
    float sx = 0.f, sy = 0.f;
    for (int k = 0; k < 32; k++) {
        int pi = ph * 32 + k;
        int n = (py * 8 + (pi >> 3)) * W_ + px * 8 + (pi & 7);
        uint32_t u = srgu32[((size_t)b * N_ + n) * 128 + cp];
        sx += lo16(u); sy += hi16(u);
    }
    if (ph == 1) part[cp] = make_float2(sx, sy);
    __syncthreads();
    if (ph == 0) {
        sx += part[cp].x; sy += part[cp].y;
        srpool[(size_t)cell * 256 + 2 * cp]     = sx * (1.0f / 64.0f);
        srpool[(size_t)cell * 256 + 2 * cp + 1] = sy * (1.0f / 64.0f);
    }
}

// ---------------- sr2: LN + kv proj + normalize (bf16 outputs) ----------------
__global__ __launch_bounds__(256) void k_sr2(
    const float* __restrict__ srpool,
    const float* __restrict__ Wkv, const float* __restrict__ bkv,
    const float* __restrict__ ln_g, const float* __restrict__ ln_b,
    ushort* __restrict__ kpn_u, ushort* __restrict__ vpu)
{
    const int cell = blockIdx.x;
    const int t = threadIdx.x;
    __shared__ float xp[C_];
    __shared__ float red[4];

    float acc = srpool[(size_t)cell * C_ + t];
    float mean = block_sum(acc, red) * (1.0f / C_);
    float dv = acc - mean;
    float var = block_sum(dv * dv, red) * (1.0f / C_);
    float xpv = dv * rsqrtf(var + 1e-5f) * ln_g[t] + ln_b[t];
    xp[t] = xpv;
    __syncthreads();

    float ak = bkv[t];
    float av = bkv[C_ + t];
    for (int c = 0; c < C_; c++) {
        float xv = xp[c];
        ak += xv * Wkv[c * 2 * C_ + t];
        av += xv * Wkv[c * 2 * C_ + C_ + t];
    }
    float nk = fmaxf(sqrtf(half_reduce(ak * ak)), 1e-12f);
    size_t o = (size_t)cell * C_ + t;
    kpn_u[o] = f2bf_u(ak / nk);
    vpu[o]  = f2bf_u(av);
}

// ---------------- plog: pooled logits (32 tokens/block) ----------------
__global__ __launch_bounds__(256) void k_plog(
    const float* __restrict__ Z, const uint32_t* __restrict__ kpnu,
    ushort* __restrict__ plogu)
{
    const int b  = blockIdx.x / (N_ / 32);
    const int t0 = (blockIdx.x % (N_ / 32)) * 32;
    const int t = threadIdx.x;
    __shared__ __align__(16) uint32_t kps[49 * SD];
    for (int idx = t; idx < 49 * 128; idx += 256) {
        int p = idx >> 7, jj = idx & 127;
        uint32_t val = kpnu[((size_t)b * P_ + p) * 128 + jj];
        int h2 = jj >> 4, j = jj & 15;
        kps[p * SD + h2 * 16 + ((j + 2 * h2) & 15)] = val;
    }
    const int tok = t >> 3, h = t & 7;
    const size_t flat = (size_t)b * N_ + t0 + tok;
    float4 qf[8];
    const float4* qrow = reinterpret_cast<const float4*>(Z + flat * ZSTR + h * HD);
#pragma unroll
    for (int j = 0; j < 8; j++) qf[j] = qrow[j];
    __syncthreads();

    size_t obase = (flat * NH + h) * PLSTR;
    uint32_t* out32 = (uint32_t*)(plogu + obase);
#pragma unroll
    for (int pp = 0; pp < 24; pp++) {
        float a0 = dot32(&kps[(2 * pp) * SD + h * 16], qf, h);
        float a1 = dot32(&kps[(2 * pp + 1) * SD + h * 16], qf, h);
        out32[pp] = (uint32_t)f2bf_u(a0) | ((uint32_t)f2bf_u(a1) << 16);
    }
    float a48 = dot32(&kps[48 * SD + h * 16], qf, h);
    plogu[obase + 48] = f2bf_u(a48);
}

// ---------------- coef: window logits + softmax + merged coef (4x4 tile) ----------------
__global__ __launch_bounds__(256) void k_coef(
    float* __restrict__ Z,
    const uint32_t* __restrict__ knu,
    const ushort* __restrict__ plogu)
{
    const int b    = blockIdx.x / 196;
    const int tile = blockIdx.x % 196;
    const int ty = tile / 14, tx = tile % 14;
    const int t = threadIdx.x;
    __shared__ __align__(16) uint32_t ks[64 * SD];

    for (int idx = t; idx < 64 * 64; idx += 256) {
        int r = idx >> 6, u = idx & 63;
        int gy = ty * 4 + (r >> 3) - 2, gx = tx * 4 + (r & 7) - 2;
        uint32_t v0 = 0, v1 = 0;
        if (gy >= 0 && gy < H_ && gx >= 0 && gx < W_) {
            uint2 val = *reinterpret_cast<const uint2*>(
                knu + ((size_t)b * N_ + gy * W_ + gx) * 128 + 2 * u);
            v0 = val.x; v1 = val.y;
        }
        int jj = 2 * u;
        int h2 = jj >> 4, j0 = jj & 15;
        ks[r * SD + h2 * 16 + ((j0 + 2 * h2) & 15)]     = v0;
        ks[r * SD + h2 * 16 + ((j0 + 1 + 2 * h2) & 15)] = v1;
    }

    const int pair = t >> 1, half = t & 1;
    const int tok = pair >> 3, h = pair & 7;
    const int iy = tok >> 2, ix = tok & 3;
    const int gy0 = ty * 4 + iy, gx0 = tx * 4 + ix;
    const size_t flat = (size_t)b * N_ + gy0 * W_ + gx0;

    float4 qf[8];
    {
        const float4* qrow = reinterpret_cast<const float4*>(Z + flat * ZSTR + h * HD);
#pragma unroll
        for (int j = 0; j < 8; j++) qf[j] = qrow[j];
    }
    __syncthreads();

    float lgW[13], tokm[13];
    const ushort* tokcu = (const ushort*)(Z + flat * ZSTR + 256) + h * 34;
#pragma unroll
    for (int k = 0; k < 13; k++) {
        int l = half * 13 + k;
        bool slot = (l < 25);
        int dy = l / 5 - 2, dx = l % 5 - 2;
        int gy = gy0 + dy, gx = gx0 + dx;
        bool in = slot && gy >= 0 && gy < H_ && gx >= 0 && gx < W_;
        float a = -INFINITY;
        if (in) {
            int r = (iy + dy + 2) * 8 + (ix + dx + 2);
            a = dot32(&ks[r * SD + h * 16], qf, h);
        }
        lgW[k] = a;
        float tm = 0.f;
        if (slot) {
            bool inner = (dy >= -1 && dy <= 1 && dx >= -1 && dx <= 1);
            tm = bfu2f(tokcu[9 + l]);
            if (inner) tm += bfu2f(tokcu[(dy + 1) * 3 + (dx + 1)]);
        }
        tokm[k] = tm;
    }
    float lgP[25];
    {
        const ushort* pl = plogu + (flat * NH + h) * PLSTR + half * 24;
#pragma unroll
        for (int k = 0; k < 25; k++)
            lgP[k] = (k < 24 + half) ? bfu2f(pl[k]) : -INFINITY;
    }

    float m = -INFINITY;
#pragma unroll
    for (int k = 0; k < 13; k++) m = fmaxf(m, lgW[k]);
#pragma unroll
    for (int k = 0; k < 25; k++) m = fmaxf(m, lgP[k]);
    float e = 0.f;
#pragma unroll
    for (int k = 0; k < 13; k++) {
        int l = half * 13 + k;
        int dy = l / 5 - 2, dx = l % 5 - 2;
        bool inner = (l < 25) && (dy >= -1 && dy <= 1 && dx >= -1 && dx <= 1);
        e += (inner ? 2.0f : 1.0f) * __expf(lgW[k] - m);
    }
#pragma unroll
    for (int k = 0; k < 25; k++) e += __expf(lgP[k] - m);

    float mo = __shfl_xor(m, 1);
    float eo = __shfl_xor(e, 1);
    float mN = fmaxf(m, mo);
    float etot = e * __expf(m - mN) + eo * __expf(mo - mN);
    float scale = __expf(m - mN) / etot;

    __syncthreads();   // all Z (q, tokc) reads done before coef overwrite

    ushort* coefu = (ushort*)(Z + flat * ZSTR);  // [h][76]: 0..24 window, 25..73 pooled
#pragma unroll
    for (int k = 0; k < 13; k++) {
        int l = half * 13 + k;
        if (l < 25) {
            int dy = l / 5 - 2, dx = l % 5 - 2;
            bool inner = (dy >= -1 && dy <= 1 && dx >= -1 && dx <= 1);
            float w = (inner ? 2.0f : 1.0f) * __expf(lgW[k] - m) * scale + tokm[k];
            coefu[h * 76 + l] = f2bf_u(w);
        }
    }
#pragma unroll
    for (int k = 0; k < 25; k++) {
        if (k < 24 + half) {
            int p = half * 24 + k;
            coefu[h * 76 + 25 + p] = f2bf_u(__expf(lgP[k] - m) * scale);
        }
    }
}

// ---------------- av: weighted sums, thread=(token, 8ch), uint4 loads ----------------
__global__ __launch_bounds__(256) void k_av(
    const float* __restrict__ Z,          // coef (ushort view)
    const uint32_t* __restrict__ vu,      // v bf16 pairs
    const ushort* __restrict__ vpu,       // vp bf16 plane
    uint32_t* __restrict__ pre_bfu)
{
    const int r0 = blockIdx.x * ROWS;
    const int t = threadIdx.x;
    const int tk = t >> 5, g = t & 31;
    const int h = g >> 2;
    __shared__ ushort coefS[ROWS * 608];

    const int b = r0 / N_;
    {
        uint32_t* cS = (uint32_t*)coefS;
        for (int idx = t; idx < ROWS * 304; idx += 256) {
            int tt = idx / 304, d = idx % 304;
            cS[tt * 304 + d] = ((const uint32_t*)(Z + (size_t)(r0 + tt) * ZSTR))[d];
        }
    }
    __syncthreads();

    const int n0 = r0 % N_;
    const int y = n0 / W_, x = n0 % W_ + tk;
    const ushort* cf = &coefS[tk * 608 + h * 76];

    float a0x = 0.f, a0y = 0.f, a1x = 0.f, a1y = 0.f;
    float a2x = 0.f, a2y = 0.f, a3x = 0.f, a3y = 0.f;

#pragma unroll
    for (int l = 0; l < 25; l++) {
        int dy = l / 5 - 2, dx = l % 5 - 2;
        int yy = y + dy, xx2 = x + dx;
        if (yy < 0 || yy >= H_ || xx2 < 0 || xx2 >= W_) continue;
        float w = bfu2f(cf[l]);
        uint4 vv = *reinterpret_cast<const uint4*>(vu + ((size_t)b * N_ + yy * W_ + xx2) * 128 + 4 * g);
        a0x += w * lo16(vv.x); a0y += w * hi16(vv.x);
        a1x += w * lo16(vv.y); a1y += w * hi16(vv.y);
        a2x += w * lo16(vv.z); a2y += w * hi16(vv.z);
        a3x += w * lo16(vv.w); a3y += w * hi16(vv.w);
    }
#pragma unroll 7
    for (int p = 0; p < 49; p++) {
        float w = bfu2f(cf[25 + p]);
        uint4 vv = *reinterpret_cast<const uint4*>(
            (const uint32_t*)(vpu + ((size_t)b * P_ + p) * 256) + 4 * g);
        a0x += w * lo16(vv.x); a0y += w * hi16(vv.x);
        a1x += w * lo16(vv.y); a1y += w * hi16(vv.y);
        a2x += w * lo16(vv.z); a2y += w * hi16(vv.z);
        a3x += w * lo16(vv.w); a3y += w * hi16(vv.w);
    }
    uint4 o;
    o.x = (uint32_t)f2bf_u(a0x) | ((uint32_t)f2bf_u(a0y) << 16);
    o.y = (uint32_t)f2bf_u(a1x) | ((uint32_t)f2bf_u(a1y) << 16);
    o.z = (uint32_t)f2bf_u(a2x) | ((uint32_t)f2bf_u(a2y) << 16);
    o.w = (uint32_t)f2bf_u(a3x) | ((uint32_t)f2bf_u(a3y) << 16);
    *reinterpret_cast<uint4*>(pre_bfu + (size_t)(r0 + tk) * 128 + 4 * g) = o;
}

extern "C" void kernel_launch(void* const* d_in, const int* in_sizes, int n_in,
                              void* d_out, int out_size, void* d_ws, size_t ws_size,
                              hipStream_t stream)
{
    (void)in_sizes; (void)n_in; (void)out_size; (void)ws_size;
    const float* x     = (const float*)d_in[0];
    const float* Wq    = (const float*)d_in[1];
    const float* bq    = (const float*)d_in[2];
    const float* Wkv   = (const float*)d_in[3];
    const float* bkv   = (const float*)d_in[4];
    const float* Wsr   = (const float*)d_in[5];
    const float* bsr   = (const float*)d_in[6];
    const float* ln_g  = (const float*)d_in[7];
    const float* ln_b  = (const float*)d_in[8];
    const float* tok1  = (const float*)d_in[9];
    const float* bias1 = (const float*)d_in[10];
    const float* tok2  = (const float*)d_in[11];
    const float* bias2 = (const float*)d_in[12];
    const float* Wproj = (const float*)d_in[13];
    const float* bproj = (const float*)d_in[14];
    float* out = (float*)d_out;

    const size_t nz    = (size_t)B_ * N_ * ZSTR;   // dwords
    const size_t nhalf = (size_t)B_ * N_ * 128;    // dwords per bf16 plane

    float*    Zb     = (float*)d_ws;
    uint32_t* xbf    = (uint32_t*)(Zb + nz);       // aliased: pre_bf after GEMMs
    uint32_t* vu     = xbf + nhalf;
    uint32_t* knu    = vu + nhalf;
    uint32_t* srgu   = knu + nhalf;                // aliased: qn bf16 plane before gemm<3>
    ushort*   WTus   = (ushort*)(srgu + nhalf);    // 1024*256 bf16
    ushort*   WTpus  = WTus + 1024 * 256;          // 256*256 bf16
    ushort*   TDus   = WTpus + 256 * 256;          // 320*256 bf16 (tok block-diag)
    float*    biasT  = (float*)(TDus + 320 * 256); // 320 f32
    ushort*   vpu    = (ushort*)(biasT + 320);     // B*P*256 bf16
    uint32_t* kpnu   = (uint32_t*)(vpu + (size_t)B_ * P_ * 256);
    float*    srpool = (float*)(kpnu + (size_t)B_ * P_ * 128);

    ushort* plogu = (ushort*)d_out;   // pooled logits live in d_out until final GEMM
    ushort* qnu   = (ushort*)srgu;    // qn bf16 plane (dead after gemm<5>)

    dim3 g64(196, 4);
    dim3 g5(196, 5);

    k_prep<<<2048, 256, 0, stream>>>(x, Wq, Wkv, Wsr, Wproj,
                                     tok1, bias1, tok2, bias2,
                                     (ushort*)xbf, WTus, WTpus, TDus, biasT);
    k_gemm<0><<<g64, 256, 0, stream>>>((ushort*)xbf, WTus,             bq,        Zb, qnu);
    k_gemm<5><<<g5,  256, 0, stream>>>(qnu,          TDus,             biasT,     Zb, nullptr);
    k_gemm<1><<<g64, 256, 0, stream>>>((ushort*)xbf, WTus + 256 * 256, bkv,       nullptr, (ushort*)knu);
    k_gemm<2><<<g64, 256, 0, stream>>>((ushort*)xbf, WTus + 512 * 256, bkv + 256, nullptr, (ushort*)vu);
    k_gemm<3><<<g64, 256, 0, stream>>>((ushort*)xbf, WTus + 768 * 256, bsr,       nullptr, (ushort*)srgu);
    k_pool<<<B_ * P_, 256, 0, stream>>>(srgu, srpool);
    k_sr2<<<B_ * P_, 256, 0, stream>>>(srpool, Wkv, bkv, ln_g, ln_b, (ushort*)kpnu, vpu);
    k_plog<<<B_ * (N_ / 32), 256, 0, stream>>>(Zb, kpnu, plogu);
    k_coef<<<B_ * 196, 256, 0, stream>>>(Zb, knu, plogu);
    k_av<<<B_ * N_ / ROWS, 256, 0, stream>>>(Zb, vu, vpu, xbf);  // pre overwrites xbf
    k_gemm<4><<<g64, 256, 0, stream>>>((ushort*)xbf, WTpus, bproj, out, nullptr);
}

// Round 8
// 152.781 us; speedup vs baseline: 5.6777x; 1.0531x over previous
//
#include <hip/hip_runtime.h>
#include <hip/hip_bf16.h>

using bf16 = __hip_bfloat16;

#define B_  4
#define H_  56
#define W_  56
#define N_  3136
#define C_  256
#define NH  8
#define HD  32
#define P_  49
#define PH  7
#define ROWS 8
#define SD  132          // LDS row stride (dwords) for swizzled bf16-pair rows
#define TOKC 272         // 8 heads * 34 token coefficients
#define ZSTR 392         // Z record stride (dwords): 256 qn f32 + 136 dw (272 bf16 tokc)
#define PLSTR 52         // plog stride (ushorts) per (token,head)

typedef __attribute__((ext_vector_type(8))) short short8;
typedef __attribute__((ext_vector_type(4))) float f32x4;

__device__ __forceinline__ float bfu2f(ushort u) { return __uint_as_float((uint32_t)u << 16); }
__device__ __forceinline__ ushort f2bf_u(float f) {
    uint32_t u = __float_as_uint(f);
    uint32_t r = (u + 0x7FFFu + ((u >> 16) & 1u)) >> 16;
    return (ushort)r;
}
__device__ __forceinline__ uint32_t pk2(float a, float b) {
    return (uint32_t)f2bf_u(a) | ((uint32_t)f2bf_u(b) << 16);
}
__device__ __forceinline__ float lo16(uint32_t u) { return __uint_as_float(u << 16); }
__device__ __forceinline__ float hi16(uint32_t u) { return __uint_as_float(u & 0xffff0000u); }

__device__ __forceinline__ float half_reduce(float v) {
#pragma unroll
    for (int m = 16; m >= 1; m >>= 1) v += __shfl_xor(v, m);
    return v;
}

__device__ __forceinline__ float block_sum(float val, float* red) {
#pragma unroll
    for (int m = 32; m >= 1; m >>= 1) val += __shfl_xor(val, m);
    __syncthreads();
    if ((threadIdx.x & 63) == 0) red[threadIdx.x >> 6] = val;
    __syncthreads();
    return red[0] + red[1] + red[2] + red[3];
}

// dot of q (8x float4) with a swizzled bf16-pair LDS row segment for head h2
__device__ __forceinline__ float dot32(const uint32_t* row, const float4* qf, int h2) {
    float a = 0.f;
#pragma unroll
    for (int jp = 0; jp < 8; jp++) {
        int pc = (2 * jp + 2 * h2) & 15;
        uint2 w = *reinterpret_cast<const uint2*>(row + pc);
        float4 q = qf[jp];
        a += q.x * lo16(w.x);
        a += q.y * hi16(w.x);
        a += q.z * lo16(w.y);
        a += q.w * hi16(w.y);
    }
    return a;
}

// ---------------- prep: weight transposes + tok block-diag (weights only) ----------------
__global__ __launch_bounds__(256) void k_prep(
    const float* __restrict__ Wq, const float* __restrict__ Wkv,
    const float* __restrict__ Wsr, const float* __restrict__ Wproj,
    const float* __restrict__ tok1, const float* __restrict__ bias1,
    const float* __restrict__ tok2, const float* __restrict__ bias2,
    ushort* __restrict__ WT, ushort* __restrict__ WTp,
    ushort* __restrict__ TD, float* __restrict__ biasT)
{
    const int gid = blockIdx.x * 256 + threadIdx.x;
    const int gs = gridDim.x * 256;
    for (int i = gid; i < 1024 * 256; i += gs) {
        int o = i >> 8, c = i & 255;
        float w = (o < 256) ? Wq[c * 256 + o]
                : (o < 768) ? Wkv[c * 512 + (o - 256)]
                            : Wsr[c * 256 + (o - 768)];
        WT[i] = f2bf_u(w);
    }
    for (int i = gid; i < 256 * 256; i += gs) {
        int o = i >> 8, c = i & 255;
        WTp[i] = f2bf_u(Wproj[c * 256 + o]);
    }
    for (int i = gid; i < 320 * 256; i += gs) {
        int j = i >> 8, k = i & 255;
        float val = 0.f;
        if (j < TOKC) {
            int h = j / 34, l = j % 34;
            if ((k >> 5) == h) {
                int d = k & 31;
                val = (l < 9) ? tok1[(h * HD + d) * 9 + l]
                              : tok2[(h * HD + d) * 25 + (l - 9)];
            }
        }
        TD[i] = f2bf_u(val);
    }
    for (int i = gid; i < 320; i += gs) {
        float bv = 0.f;
        if (i < TOKC) {
            int h = i / 34, l = i % 34;
            bv = (l < 9) ? bias1[h * 9 + l] : bias2[h * 25 + (l - 9)];
        }
        biasT[i] = bv;
    }
}

// ---------------- merged input GEMM: 64 rows x 512 cols (8 chunks), K=256 ----------------
// grid (196, 2): y=0 -> cols 0..511 (modes q,k); y=1 -> cols 512..1023 (modes v,sr)
__global__ __launch_bounds__(256) void k_gemm_in(
    const float* __restrict__ xf,     // [12544][256] f32
    const ushort* __restrict__ WT,    // [1024][256] bf16
    const float* __restrict__ bq, const float* __restrict__ bkv,
    const float* __restrict__ bsr,
    float* __restrict__ Zb, ushort* __restrict__ qnu,
    ushort* __restrict__ knu, ushort* __restrict__ vu, ushort* __restrict__ srgu)
{
    const int r0 = blockIdx.x * 64;
    const int halfy = blockIdx.y;
    const int t = threadIdx.x;
    __shared__ __align__(16) ushort As[64 * 264];
    __shared__ __align__(16) ushort Bs[64 * 264];

    // stage A (f32 -> bf16 pack), 64 elems/thread
#pragma unroll
    for (int i = 0; i < 8; i++) {
        int chunk = t + i * 256;
        int row = chunk >> 5, ks8 = (chunk & 31) * 8;
        const float* src = xf + (size_t)(r0 + row) * 256 + ks8;
        float4 f0 = *(const float4*)(src);
        float4 f1 = *(const float4*)(src + 4);
        uint4 o;
        o.x = pk2(f0.x, f0.y); o.y = pk2(f0.z, f0.w);
        o.z = pk2(f1.x, f1.y); o.w = pk2(f1.z, f1.w);
        *(uint4*)(As + row * 264 + ks8) = o;
    }
    __syncthreads();

    const int w = t >> 6, lane = t & 63;
    const int arow = w * 16 + (lane & 15);
    const int k0 = (lane >> 4) * 8;
    const int colq = lane & 15;
    const int rb = r0 + w * 16 + (lane >> 4) * 4;

    short8 areg[8];
#pragma unroll
    for (int kk = 0; kk < 8; kk++)
        areg[kk] = *(const short8*)(As + arow * 264 + kk * 32 + k0);

    for (int cc = 0; cc < 8; cc++) {
        const int cb = halfy * 512 + cc * 64;
        const int mode = cb >> 8;
        const int cm = cb & 255;

        __syncthreads();   // previous chunk's Bs reads done
#pragma unroll
        for (int i = 0; i < 8; i++) {
            int chunk = t + i * 256;
            int row = chunk >> 5, ks8 = (chunk & 31) * 8;
            *(uint4*)(Bs + row * 264 + ks8) =
                *(const uint4*)(WT + (size_t)(cb + row) * 256 + ks8);
        }
        __syncthreads();

        f32x4 acc[4];
#pragma unroll
        for (int ct = 0; ct < 4; ct++) acc[ct] = (f32x4){0.f, 0.f, 0.f, 0.f};
#pragma unroll
        for (int kk = 0; kk < 8; kk++) {
#pragma unroll
            for (int ct = 0; ct < 4; ct++) {
                short8 b = *(const short8*)(Bs + (ct * 16 + colq) * 264 + kk * 32 + k0);
                acc[ct] = __builtin_amdgcn_mfma_f32_16x16x32_bf16(areg[kk], b, acc[ct], 0, 0, 0);
            }
        }

        const float* bp = (mode == 0) ? bq : (mode == 1) ? bkv : (mode == 2) ? (bkv + 256) : bsr;
#pragma unroll
        for (int ct = 0; ct < 4; ct++) {
            float bv = bp[cm + ct * 16 + colq];
#pragma unroll
            for (int j = 0; j < 4; j++) acc[ct][j] += bv;
        }

        if (mode <= 1) {
            // per-row L2 normalize per head (32 cols = ctile pairs)
#pragma unroll
            for (int hp = 0; hp < 2; hp++) {
#pragma unroll
                for (int j = 0; j < 4; j++) {
                    float ss = acc[2 * hp][j] * acc[2 * hp][j] + acc[2 * hp + 1][j] * acc[2 * hp + 1][j];
                    ss += __shfl_xor(ss, 1); ss += __shfl_xor(ss, 2);
                    ss += __shfl_xor(ss, 4); ss += __shfl_xor(ss, 8);
                    float inv = 1.0f / fmaxf(sqrtf(ss), 1e-12f);
                    acc[2 * hp][j] *= inv; acc[2 * hp + 1][j] *= inv;
                }
            }
        } else if (mode == 3) {
#pragma unroll
            for (int ct = 0; ct < 4; ct++)
#pragma unroll
                for (int j = 0; j < 4; j++) {
                    float s = acc[ct][j];
                    acc[ct][j] = 0.5f * s * (1.0f + erff(s * 0.70710678118654752f));
                }
        }

#pragma unroll
        for (int ct = 0; ct < 4; ct++) {
            int gcol = cm + ct * 16 + colq;
#pragma unroll
            for (int j = 0; j < 4; j++) {
                float vvv = acc[ct][j];
                size_t ro = (size_t)(rb + j);
                if (mode == 0) {
                    Zb[ro * ZSTR + gcol] = vvv;
                    qnu[ro * 256 + gcol] = f2bf_u(vvv);
                } else if (mode == 1) {
                    knu[ro * 256 + gcol] = f2bf_u(vvv);
                } else if (mode == 2) {
                    vu[ro * 256 + gcol] = f2bf_u(vvv);
                } else {
                    srgu[ro * 256 + gcol] = f2bf_u(vvv);
                }
            }
        }
    }
}

// ---------------- bf16-A GEMM 64x64 tile, K=256. MODE: 4=proj(f32->out) 5=tokc ----------------
template <int MODE>
__global__ __launch_bounds__(256) void k_gemm(
    const ushort* __restrict__ Abf,
    const ushort* __restrict__ WT,
    const float*  __restrict__ bias,
    float* __restrict__ dstF)
{
    const int r0 = blockIdx.x * 64;
    const int cb = blockIdx.y * 64;
    const int t = threadIdx.x;
    __shared__ __align__(16) ushort As[64 * 264];
    __shared__ __align__(16) ushort Bs[64 * 264];

#pragma unroll
    for (int i = 0; i < 8; i++) {
        int chunk = t + i * 256;
        int row = chunk >> 5, ks = (chunk & 31) * 8;
        *(uint4*)(As + row * 264 + ks) = *(const uint4*)(Abf + (size_t)(r0 + row) * 256 + ks);
        *(uint4*)(Bs + row * 264 + ks) = *(const uint4*)(WT + (size_t)(cb + row) * 256 + ks);
    }
    __syncthreads();

    const int w = t >> 6, lane = t & 63;
    const int arow = w * 16 + (lane & 15);
    const int k0 = (lane >> 4) * 8;
    f32x4 acc[4];
#pragma unroll
    for (int ct = 0; ct < 4; ct++) acc[ct] = (f32x4){0.f, 0.f, 0.f, 0.f};

#pragma unroll
    for (int kk = 0; kk < 8; kk++) {
        short8 a = *(const short8*)(As + arow * 264 + kk * 32 + k0);
#pragma unroll
        for (int ct = 0; ct < 4; ct++) {
            short8 b = *(const short8*)(Bs + (ct * 16 + (lane & 15)) * 264 + kk * 32 + k0);
            acc[ct] = __builtin_amdgcn_mfma_f32_16x16x32_bf16(a, b, acc[ct], 0, 0, 0);
        }
    }

    const int colq = lane & 15;
    const int rb = r0 + w * 16 + (lane >> 4) * 4;
#pragma unroll
    for (int ct = 0; ct < 4; ct++) {
        float bv = bias[cb + ct * 16 + colq];
#pragma unroll
        for (int j = 0; j < 4; j++) acc[ct][j] += bv;
    }

#pragma unroll
    for (int ct = 0; ct < 4; ct++) {
        int gcol = cb + ct * 16 + colq;
#pragma unroll
        for (int j = 0; j < 4; j++) {
            if (MODE == 4) {
                dstF[(size_t)(rb + j) * 256 + gcol] = acc[ct][j];
            } else {
                if (gcol < TOKC)
                    ((ushort*)(dstF + (size_t)(rb + j) * ZSTR + 256))[gcol] = f2bf_u(acc[ct][j]);
            }
        }
    }
}

// ---------------- srt: pool + LN + kv proj + normalize (fused) ----------------
__global__ __launch_bounds__(256) void k_srt(
    const uint32_t* __restrict__ srgu32,
    const float* __restrict__ Wkv, const float* __restrict__ bkv,
    const float* __restrict__ ln_g, const float* __restrict__ ln_b,
    ushort* __restrict__ kpn_u, ushort* __restrict__ vpu)
{
    const int cell = blockIdx.x;   // b*P + p
    const int b = cell / P_, p = cell % P_;
    const int py = p / PH, px = p % PH;
    const int t = threadIdx.x;
    const int ph = t >> 7, cp = t & 127;
    __shared__ float xp[C_];
    __shared__ float red[4];

    float sx = 0.f, sy = 0.f;
    for (int k = 0; k < 32; k++) {
        int pi = ph * 32 + k;
        int n = (py * 8 + (pi >> 3)) * W_ + px * 8 + (pi & 7);
        uint32_t u = srgu32[((size_t)b * N_ + n) * 128 + cp];
        sx += lo16(u); sy += hi16(u);
    }
    if (ph == 1) { xp[2 * cp] = sx; xp[2 * cp + 1] = sy; }
    __syncthreads();
    if (ph == 0) {
        xp[2 * cp]     = (xp[2 * cp] + sx) * (1.0f / 64.0f);
        xp[2 * cp + 1] = (xp[2 * cp + 1] + sy) * (1.0f / 64.0f);
    }
    __syncthreads();

    float acc = xp[t];
    float mean = block_sum(acc, red) * (1.0f / C_);
    float dv = acc - mean;
    float var = block_sum(dv * dv, red) * (1.0f / C_);
    float xpv = dv * rsqrtf(var + 1e-5f) * ln_g[t] + ln_b[t];
    __syncthreads();
    xp[t] = xpv;
    __syncthreads();

    float ak = bkv[t];
    float av = bkv[C_ + t];
    for (int c = 0; c < C_; c++) {
        float xv = xp[c];
        ak += xv * Wkv[c * 2 * C_ + t];
        av += xv * Wkv[c * 2 * C_ + C_ + t];
    }
    float nk = fmaxf(sqrtf(half_reduce(ak * ak)), 1e-12f);
    size_t o = (size_t)cell * C_ + t;
    kpn_u[o] = f2bf_u(ak / nk);
    vpu[o]  = f2bf_u(av);
}

// ---------------- plog: pooled logits (32 tokens/block) ----------------
__global__ __launch_bounds__(256) void k_plog(
    const float* __restrict__ Z, const uint32_t* __restrict__ kpnu,
    ushort* __restrict__ plogu)
{
    const int b  = blockIdx.x / (N_ / 32);
    const int t0 = (blockIdx.x % (N_ / 32)) * 32;
    const int t = threadIdx.x;
    __shared__ __align__(16) uint32_t kps[49 * SD];
    for (int idx = t; idx < 49 * 128; idx += 256) {
        int p = idx >> 7, jj = idx & 127;
        uint32_t val = kpnu[((size_t)b * P_ + p) * 128 + jj];
        int h2 = jj >> 4, j = jj & 15;
        kps[p * SD + h2 * 16 + ((j + 2 * h2) & 15)] = val;
    }
    const int tok = t >> 3, h = t & 7;
    const size_t flat = (size_t)b * N_ + t0 + tok;
    float4 qf[8];
    const float4* qrow = reinterpret_cast<const float4*>(Z + flat * ZSTR + h * HD);
#pragma unroll
    for (int j = 0; j < 8; j++) qf[j] = qrow[j];
    __syncthreads();

    size_t obase = (flat * NH + h) * PLSTR;
    uint32_t* out32 = (uint32_t*)(plogu + obase);
#pragma unroll
    for (int pp = 0; pp < 24; pp++) {
        float a0 = dot32(&kps[(2 * pp) * SD + h * 16], qf, h);
        float a1 = dot32(&kps[(2 * pp + 1) * SD + h * 16], qf, h);
        out32[pp] = (uint32_t)f2bf_u(a0) | ((uint32_t)f2bf_u(a1) << 16);
    }
    float a48 = dot32(&kps[48 * SD + h * 16], qf, h);
    plogu[obase + 48] = f2bf_u(a48);
}

// ---------------- coef: window logits + softmax + merged coef (4x4 tile) ----------------
__global__ __launch_bounds__(256) void k_coef(
    float* __restrict__ Z,
    const uint32_t* __restrict__ knu,
    const ushort* __restrict__ plogu)
{
    const int b    = blockIdx.x / 196;
    const int tile = blockIdx.x % 196;
    const int ty = tile / 14, tx = tile % 14;
    const int t = threadIdx.x;
    __shared__ __align__(16) uint32_t ks[64 * SD];

    for (int idx = t; idx < 64 * 64; idx += 256) {
        int r = idx >> 6, u = idx & 63;
        int gy = ty * 4 + (r >> 3) - 2, gx = tx * 4 + (r & 7) - 2;
        uint32_t v0 = 0, v1 = 0;
        if (gy >= 0 && gy < H_ && gx >= 0 && gx < W_) {
            uint2 val = *reinterpret_cast<const uint2*>(
                knu + ((size_t)b * N_ + gy * W_ + gx) * 128 + 2 * u);
            v0 = val.x; v1 = val.y;
        }
        int jj = 2 * u;
        int h2 = jj >> 4, j0 = jj & 15;
        ks[r * SD + h2 * 16 + ((j0 + 2 * h2) & 15)]     = v0;
        ks[r * SD + h2 * 16 + ((j0 + 1 + 2 * h2) & 15)] = v1;
    }

    const int pair = t >> 1, half = t & 1;
    const int tok = pair >> 3, h = pair & 7;
    const int iy = tok >> 2, ix = tok & 3;
    const int gy0 = ty * 4 + iy, gx0 = tx * 4 + ix;
    const size_t flat = (size_t)b * N_ + gy0 * W_ + gx0;

    float4 qf[8];
    {
        const float4* qrow = reinterpret_cast<const float4*>(Z + flat * ZSTR + h * HD);
#pragma unroll
        for (int j = 0; j < 8; j++) qf[j] = qrow[j];
    }
    __syncthreads();

    float lgW[13], tokm[13];
    const ushort* tokcu = (const ushort*)(Z + flat * ZSTR + 256) + h * 34;
#pragma unroll
    for (int k = 0; k < 13; k++) {
        int l = half * 13 + k;
        bool slot = (l < 25);
        int dy = l / 5 - 2, dx = l % 5 - 2;
        int gy = gy0 + dy, gx = gx0 + dx;
        bool in = slot && gy >= 0 && gy < H_ && gx >= 0 && gx < W_;
        float a = -INFINITY;
        if (in) {
            int r = (iy + dy + 2) * 8 + (ix + dx + 2);
            a = dot32(&ks[r * SD + h * 16], qf, h);
        }
        lgW[k] = a;
        float tm = 0.f;
        if (slot) {
            bool inner = (dy >= -1 && dy <= 1 && dx >= -1 && dx <= 1);
            tm = bfu2f(tokcu[9 + l]);
            if (inner) tm += bfu2f(tokcu[(dy + 1) * 3 + (dx + 1)]);
        }
        tokm[k] = tm;
    }
    float lgP[25];
    {
        const ushort* pl = plogu + (flat * NH + h) * PLSTR + half * 24;
#pragma unroll
        for (int k = 0; k < 25; k++)
            lgP[k] = (k < 24 + half) ? bfu2f(pl[k]) : -INFINITY;
    }

    float m = -INFINITY;
#pragma unroll
    for (int k = 0; k < 13; k++) m = fmaxf(m, lgW[k]);
#pragma unroll
    for (int k = 0; k < 25; k++) m = fmaxf(m, lgP[k]);
    float e = 0.f;
#pragma unroll
    for (int k = 0; k < 13; k++) {
        int l = half * 13 + k;
        int dy = l / 5 - 2, dx = l % 5 - 2;
        bool inner = (l < 25) && (dy >= -1 && dy <= 1 && dx >= -1 && dx <= 1);
        e += (inner ? 2.0f : 1.0f) * __expf(lgW[k] - m);
    }
#pragma unroll
    for (int k = 0; k < 25; k++) e += __expf(lgP[k] - m);

    float mo = __shfl_xor(m, 1);
    float eo = __shfl_xor(e, 1);
    float mN = fmaxf(m, mo);
    float etot = e * __expf(m - mN) + eo * __expf(mo - mN);
    float scale = __expf(m - mN) / etot;

    __syncthreads();   // all Z (q, tokc) reads done before coef overwrite

    ushort* coefu = (ushort*)(Z + flat * ZSTR);  // [h][76]: 0..24 window, 25..73 pooled
#pragma unroll
    for (int k = 0; k < 13; k++) {
        int l = half * 13 + k;
        if (l < 25) {
            int dy = l / 5 - 2, dx = l % 5 - 2;
            bool inner = (dy >= -1 && dy <= 1 && dx >= -1 && dx <= 1);
            float w = (inner ? 2.0f : 1.0f) * __expf(lgW[k] - m) * scale + tokm[k];
            coefu[h * 76 + l] = f2bf_u(w);
        }
    }
#pragma unroll
    for (int k = 0; k < 25; k++) {
        if (k < 24 + half) {
            int p = half * 24 + k;
            coefu[h * 76 + 25 + p] = f2bf_u(__expf(lgP[k] - m) * scale);
        }
    }
}

// ---------------- av: weighted sums, thread=(token, 8ch), uint4 loads ----------------
__global__ __launch_bounds__(256) void k_av(
    const float* __restrict__ Z,          // coef (ushort view)
    const uint32_t* __restrict__ vu,      // v bf16 pairs
    const ushort* __restrict__ vpu,       // vp bf16 plane
    uint32_t* __restrict__ pre_bfu)
{
    const int r0 = blockIdx.x * ROWS;
    const int t = threadIdx.x;
    const int tk = t >> 5, g = t & 31;
    const int h = g >> 2;
    __shared__ ushort coefS[ROWS * 608];

    const int b = r0 / N_;
    {
        uint32_t* cS = (uint32_t*)coefS;
        for (int idx = t; idx < ROWS * 304; idx += 256) {
            int tt = idx / 304, d = idx % 304;
            cS[tt * 304 + d] = ((const uint32_t*)(Z + (size_t)(r0 + tt) * ZSTR))[d];
        }
    }
    __syncthreads();

    const int n0 = r0 % N_;
    const int y = n0 / W_, x = n0 % W_ + tk;
    const ushort* cf = &coefS[tk * 608 + h * 76];

    float a0x = 0.f, a0y = 0.f, a1x = 0.f, a1y = 0.f;
    float a2x = 0.f, a2y = 0.f, a3x = 0.f, a3y = 0.f;

#pragma unroll
    for (int l = 0; l < 25; l++) {
        int dy = l / 5 - 2, dx = l % 5 - 2;
        int yy = y + dy, xx2 = x + dx;
        if (yy < 0 || yy >= H_ || xx2 < 0 || xx2 >= W_) continue;
        float w = bfu2f(cf[l]);
        uint4 vv = *reinterpret_cast<const uint4*>(vu + ((size_t)b * N_ + yy * W_ + xx2) * 128 + 4 * g);
        a0x += w * lo16(vv.x); a0y += w * hi16(vv.x);
        a1x += w * lo16(vv.y); a1y += w * hi16(vv.y);
        a2x += w * lo16(vv.z); a2y += w * hi16(vv.z);
        a3x += w * lo16(vv.w); a3y += w * hi16(vv.w);
    }
#pragma unroll 7
    for (int p = 0; p < 49; p++) {
        float w = bfu2f(cf[25 + p]);
        uint4 vv = *reinterpret_cast<const uint4*>(
            (const uint32_t*)(vpu + ((size_t)b * P_ + p) * 256) + 4 * g);
        a0x += w * lo16(vv.x); a0y += w * hi16(vv.x);
        a1x += w * lo16(vv.y); a1y += w * hi16(vv.y);
        a2x += w * lo16(vv.z); a2y += w * hi16(vv.z);
        a3x += w * lo16(vv.w); a3y += w * hi16(vv.w);
    }
    uint4 o;
    o.x = (uint32_t)f2bf_u(a0x) | ((uint32_t)f2bf_u(a0y) << 16);
    o.y = (uint32_t)f2bf_u(a1x) | ((uint32_t)f2bf_u(a1y) << 16);
    o.z = (uint32_t)f2bf_u(a2x) | ((uint32_t)f2bf_u(a2y) << 16);
    o.w = (uint32_t)f2bf_u(a3x) | ((uint32_t)f2bf_u(a3y) << 16);
    *reinterpret_cast<uint4*>(pre_bfu + (size_t)(r0 + tk) * 128 + 4 * g) = o;
}

extern "C" void kernel_launch(void* const* d_in, const int* in_sizes, int n_in,
                              void* d_out, int out_size, void* d_ws, size_t ws_size,
                              hipStream_t stream)
{
    (void)in_sizes; (void)n_in; (void)out_size; (void)ws_size;
    const float* x     = (const float*)d_in[0];
    const float* Wq    = (const float*)d_in[1];
    const float* bq    = (const float*)d_in[2];
    const float* Wkv   = (const float*)d_in[3];
    const float* bkv   = (const float*)d_in[4];
    const float* Wsr   = (const float*)d_in[5];
    const float* bsr   = (const float*)d_in[6];
    const float* ln_g  = (const float*)d_in[7];
    const float* ln_b  = (const float*)d_in[8];
    const float* tok1  = (const float*)d_in[9];
    const float* bias1 = (const float*)d_in[10];
    const float* tok2  = (const float*)d_in[11];
    const float* bias2 = (const float*)d_in[12];
    const float* Wproj = (const float*)d_in[13];
    const float* bproj = (const float*)d_in[14];
    float* out = (float*)d_out;

    const size_t nz    = (size_t)B_ * N_ * ZSTR;   // dwords
    const size_t nhalf = (size_t)B_ * N_ * 128;    // dwords per bf16 plane

    float*    Zb     = (float*)d_ws;
    uint32_t* vu     = (uint32_t*)(Zb + nz);
    uint32_t* knu    = vu + nhalf;
    uint32_t* srgu   = knu + nhalf;                // reused as pre after k_srt
    uint32_t* qnu32  = srgu + nhalf;
    ushort*   WTus   = (ushort*)(qnu32 + nhalf);   // 1024*256 bf16
    ushort*   WTpus  = WTus + 1024 * 256;          // 256*256 bf16
    ushort*   TDus   = WTpus + 256 * 256;          // 320*256 bf16
    float*    biasT  = (float*)(TDus + 320 * 256); // 320 f32
    ushort*   vpu    = (ushort*)(biasT + 320);     // B*P*256 bf16
    uint32_t* kpnu   = (uint32_t*)(vpu + (size_t)B_ * P_ * 256);

    ushort* plogu = (ushort*)d_out;   // pooled logits live in d_out until final GEMM
    ushort* qnu   = (ushort*)qnu32;

    k_prep<<<512, 256, 0, stream>>>(Wq, Wkv, Wsr, Wproj, tok1, bias1, tok2, bias2,
                                    WTus, WTpus, TDus, biasT);
    k_gemm_in<<<dim3(196, 2), 256, 0, stream>>>(x, WTus, bq, bkv, bsr,
                                                Zb, qnu, (ushort*)knu,
                                                (ushort*)vu, (ushort*)srgu);
    k_gemm<5><<<dim3(196, 5), 256, 0, stream>>>(qnu, TDus, biasT, Zb);
    k_srt<<<B_ * P_, 256, 0, stream>>>(srgu, Wkv, bkv, ln_g, ln_b, (ushort*)kpnu, vpu);
    k_plog<<<B_ * (N_ / 32), 256, 0, stream>>>(Zb, kpnu, plogu);
    k_coef<<<B_ * 196, 256, 0, stream>>>(Zb, knu, plogu);
    k_av<<<B_ * N_ / ROWS, 256, 0, stream>>>(Zb, vu, vpu, srgu);  // pre overwrites srgu
    k_gemm<4><<<dim3(196, 4), 256, 0, stream>>>((ushort*)srgu, WTpus, bproj, out);
}